// Round 5
// baseline (723.897 us; speedup 1.0000x reference)
//
#include <hip/hip_runtime.h>
#include <hip/hip_bf16.h>

typedef unsigned short u16;
typedef unsigned int u32;

#define NB 2
#define NN 384
#define ND 128
#define NE 64
#define NHD 8
#define NHID 256
#define EH1 384
#define EH2 128
#define LN_EPS 1e-5f
#define ATT_SCALE 0.17677669529663687f  // 1/sqrt(NODE_HIDDEN//HEADS)=1/sqrt(32)

#define XOUT_ELEMS (NB * NN * ND)                 // 98304
#define ADJ_ELEMS ((size_t)NB * NN * NN * NE)     // 18874368
#define OUT_ELEMS (XOUT_ELEMS + ADJ_ELEMS)        // 18972672 f32 elements
// f32 scratch carved from the TAIL of the adj-output region (dead until
// k_edge writes it, by which time scratch is fully consumed). NO d_ws use
// anywhere (R4's d_ws write was the only new element when the container
// died; this round removes it).
#define SCRATCH_F32 (4 * XOUT_ELEMS)              // nq,nk,nv,att

typedef __attribute__((ext_vector_type(4))) float f32x4;
typedef __attribute__((ext_vector_type(8))) short s16x8;
#define MFMA16(a, b, c) __builtin_amdgcn_mfma_f32_16x16x32_bf16(a, b, c, 0, 0, 0)

__device__ __forceinline__ float bflo(u32 u) {
  return __builtin_bit_cast(float, u << 16);
}
__device__ __forceinline__ float bfhi(u32 u) {
  return __builtin_bit_cast(float, u & 0xffff0000u);
}
__device__ __forceinline__ u16 bfr(float f) {
  return __builtin_bit_cast(u16, __float2bfloat16(f));
}
__device__ __forceinline__ float bfu(u16 h) {
  return __builtin_bit_cast(float, ((u32)h) << 16);
}
__device__ __forceinline__ u32 packbf(float a, float b) {
  return (u32)bfr(a) | ((u32)bfr(b) << 16);
}
__device__ __forceinline__ float wsum64(float v) {
#pragma unroll
  for (int o = 32; o > 0; o >>= 1) v += __shfl_xor(v, o, 64);
  return v;
}
__device__ __forceinline__ float wmax64(float v) {
#pragma unroll
  for (int o = 32; o > 0; o >>= 1) v = fmaxf(v, __shfl_xor(v, o, 64));
  return v;
}

// convert 8 consecutive f32 -> one bf16 weight fragment (short8)
__device__ __forceinline__ s16x8 cvt_frag(const float* p) {
  float4 a = *(const float4*)p;
  float4 c = *(const float4*)(p + 4);
  s16x8 r;
  r[0] = (short)bfr(a.x); r[1] = (short)bfr(a.y);
  r[2] = (short)bfr(a.z); r[3] = (short)bfr(a.w);
  r[4] = (short)bfr(c.x); r[5] = (short)bfr(c.y);
  r[6] = (short)bfr(c.z); r[7] = (short)bfr(c.w);
  return r;
}

// convert 8 consecutive f32 -> hi/lo bf16 pairs (16B each)
__device__ __forceinline__ void cvt8_hl(const float* p, uint4& hi, uint4& lo) {
  float4 a = *(const float4*)p;
  float4 c = *(const float4*)(p + 4);
  float v[8] = {a.x, a.y, a.z, a.w, c.x, c.y, c.z, c.w};
  u32 hw[4], lw[4];
#pragma unroll
  for (int e = 0; e < 4; ++e) {
    u16 h0 = bfr(v[2 * e]), h1 = bfr(v[2 * e + 1]);
    u16 l0 = bfr(v[2 * e] - bfu(h0));
    u16 l1 = bfr(v[2 * e + 1] - bfu(h1));
    hw[e] = (u32)h0 | ((u32)h1 << 16);
    lw[e] = (u32)l0 | ((u32)l1 << 16);
  }
  hi.x = hw[0]; hi.y = hw[1]; hi.z = hw[2]; hi.w = hw[3];
  lo.x = lw[0]; lo.y = lw[1]; lo.z = lw[2]; lo.w = lw[3];
}

// ---------------- K1: nq/nk/nv = x @ w{q,k,v}.T (f32, plain) ----------------
__global__ void k_node_qkv(const float* __restrict__ x,
                           const float* __restrict__ wq,
                           const float* __restrict__ wk,
                           const float* __restrict__ wv,
                           float* __restrict__ nq, float* __restrict__ nk,
                           float* __restrict__ nv) {
  int row = blockIdx.x;  // b*N+i
  int t = threadIdx.x;   // 128
  __shared__ float xs[ND];
  xs[t] = x[row * ND + t];
  __syncthreads();
  float aq = 0.f, ak = 0.f, av = 0.f;
  for (int k = 0; k < ND; ++k) {
    float xv = xs[k];
    aq += xv * wq[t * ND + k];
    ak += xv * wk[t * ND + k];
    av += xv * wv[t * ND + k];
  }
  nq[row * ND + t] = aq;
  nk[row * ND + t] = ak;
  nv[row * ND + t] = av;
}

// ---------------- K2: attention via MFMA edge projections ----------------
#define ATJ 128
struct AttnS {
  u16 Ahi[ATJ][NE];     // 16KB, row stride 128B, byte ^= (row&7)<<4
  u16 Alo[ATJ][NE];     // 16KB
  float sc[NHD][NN];    // 12KB scores -> probs
  float psum[NHD][NE];  // 2KB
  float part[4][ND];    // 2KB epilogue partials
};

__global__ void __launch_bounds__(512) k_attn(
    const float* __restrict__ adj,
    const float* __restrict__ weq,
    const float* __restrict__ wek,
    const float* __restrict__ wev,
    const float* __restrict__ nq,
    const float* __restrict__ nk,
    const float* __restrict__ nv,
    float* __restrict__ att) {
  __shared__ AttnS s;
  int bi = blockIdx.x;     // b*N + i
  int b = bi / NN;
  int t = threadIdx.x;     // 512
  int h = t >> 6;          // wave = head
  int l = t & 63;
  int lr = l & 15, lk = l >> 4;

  s16x8 BQ[2], BK[2];
  {
    const float* wqp = weq + (size_t)(h * 16 + lr) * NE + lk * 8;
    const float* wkp = wek + (size_t)(h * 16 + lr) * NE + lk * 8;
    BQ[0] = cvt_frag(wqp); BQ[1] = cvt_frag(wqp + 32);
    BK[0] = cvt_frag(wkp); BK[1] = cvt_frag(wkp + 32);
  }
  float nqd = nq[(size_t)bi * ND + h * 16 + lr];

  // ---------------- pass 1: scores ----------------
  for (int tile = 0; tile < NN / ATJ; ++tile) {
    int jbase = tile * ATJ;
    __syncthreads();
    for (int p = t; p < ATJ * 8; p += 512) {
      int row = p >> 3, u = p & 7;
      const float* src = adj + ((size_t)bi * NN + jbase + row) * NE + u * 8;
      uint4 hi, lo;
      cvt8_hl(src, hi, lo);
      int byt = (row * 128 + u * 16) ^ ((row & 7) << 4);
      *(uint4*)((char*)s.Ahi + byt) = hi;
      *(uint4*)((char*)s.Alo + byt) = lo;
    }
    __syncthreads();

#pragma unroll
    for (int sub = 0; sub < ATJ / 16; ++sub) {
      int trow = sub * 16 + lr;
      int swz = (trow & 7) << 4;
      f32x4 eq = {0.f, 0.f, 0.f, 0.f}, ek = {0.f, 0.f, 0.f, 0.f};
#pragma unroll
      for (int ks = 0; ks < 2; ++ks) {
        int byt = (trow * 128 + ks * 64 + lk * 16) ^ swz;
        s16x8 ah = *(const s16x8*)((const char*)s.Ahi + byt);
        s16x8 al = *(const s16x8*)((const char*)s.Alo + byt);
        eq = MFMA16(ah, BQ[ks], eq);
        eq = MFMA16(al, BQ[ks], eq);
        ek = MFMA16(ah, BK[ks], ek);
        ek = MFMA16(al, BK[ks], ek);
      }
#pragma unroll
      for (int r = 0; r < 4; ++r) {
        int j = jbase + sub * 16 + lk * 4 + r;
        float kv = nk[((size_t)b * NN + j) * ND + h * 16 + lr] + ek[r];
        float prod = (nqd + eq[r]) * kv;
#pragma unroll
        for (int o = 8; o > 0; o >>= 1) prod += __shfl_xor(prod, o, 64);
        if (lr == 0) s.sc[h][j] = prod * ATT_SCALE;
      }
    }
  }
  __syncthreads();

  // ---------------- softmax: wave h owns row h ----------------
  {
    float vals[NN / 64];
    float m = -1e30f;
#pragma unroll
    for (int r = 0; r < NN / 64; ++r) {
      vals[r] = s.sc[h][l + 64 * r];
      m = fmaxf(m, vals[r]);
    }
    m = wmax64(m);
    float sum = 0.f;
#pragma unroll
    for (int r = 0; r < NN / 64; ++r) {
      vals[r] = __expf(vals[r] - m);
      sum += vals[r];
    }
    sum = wsum64(sum);
    float rinv = 1.f / sum;
#pragma unroll
    for (int r = 0; r < NN / 64; ++r) s.sc[h][l + 64 * r] = vals[r] * rinv;
  }

  // ---------------- pass 2: psum[h][k=l] = sum_j p * adj[j][k] -------------
  {
    float pacc = 0.f;
    const float* ab = adj + (size_t)bi * NN * NE + l;
    const float* prow = s.sc[h];
#pragma unroll 4
    for (int j = 0; j < NN; ++j) pacc += prow[j] * ab[(size_t)j * NE];
    s.psum[h][l] = pacc;
  }
  __syncthreads();

  // ---------------- epilogue: att = sum_j p nv_j + Ve psum ----------------
  {
    int c = t & 127, grp = t >> 7;  // 4-way j-split
    int hc = c >> 4;
    float acc = 0.f;
    const float* nvb = nv + (size_t)b * NN * ND + c;
    const float* pr = s.sc[hc];
#pragma unroll 4
    for (int j = grp * (NN / 4); j < (grp + 1) * (NN / 4); ++j)
      acc += pr[j] * nvb[(size_t)j * ND];
    s.part[grp][c] = acc;
  }
  __syncthreads();
  if (t < ND) {
    int c = t, hc = c >> 4;
    float acc = s.part[0][c] + s.part[1][c] + s.part[2][c] + s.part[3][c];
    const float4* wr = (const float4*)(wev + c * NE);
    const float* ps = s.psum[hc];
#pragma unroll
    for (int k4 = 0; k4 < NE / 4; ++k4) {
      float4 w4 = wr[k4];
      acc += w4.x * ps[4 * k4] + w4.y * ps[4 * k4 + 1] +
             w4.z * ps[4 * k4 + 2] + w4.w * ps[4 * k4 + 3];
    }
    att[(size_t)bi * ND + (c & 15) * NHD + hc] = acc;
  }
}

// ---------------- K3: nfc1 + LN1 + FFN + LN2, serial LN reductions ---------
struct FfnS {
  float atts[ND];
  float tvb[ND];
  float x1[ND];
  float hb[NHID];
  float stats[2];  // mean, rstd
};

__global__ void k_node_ffn(const float* __restrict__ x,
                           const float* __restrict__ att,
                           const float* __restrict__ w1, const float* __restrict__ b1,
                           const float* __restrict__ g1, const float* __restrict__ bb1,
                           const float* __restrict__ w2, const float* __restrict__ b2,
                           const float* __restrict__ w3, const float* __restrict__ b3,
                           const float* __restrict__ g2, const float* __restrict__ bb2,
                           float* __restrict__ xout) {
  __shared__ FfnS s;
  int row = blockIdx.x;
  int tid = threadIdx.x;  // 256
  if (tid < ND) s.atts[tid] = att[row * ND + tid];
  __syncthreads();

  if (tid < ND) {
    float acc = b1[tid];
    for (int k = 0; k < ND; ++k) acc += s.atts[k] * w1[tid * ND + k];
    s.tvb[tid] = x[row * ND + tid] + acc;
  }
  __syncthreads();
  if (tid == 0) {
    float m = 0.f;
    for (int k = 0; k < ND; ++k) m += s.tvb[k];
    m *= (1.f / ND);
    float v = 0.f;
    for (int k = 0; k < ND; ++k) { float d = s.tvb[k] - m; v += d * d; }
    s.stats[0] = m;
    s.stats[1] = rsqrtf(v * (1.f / ND) + LN_EPS);
  }
  __syncthreads();
  if (tid < ND)
    s.x1[tid] = (s.tvb[tid] - s.stats[0]) * s.stats[1] * g1[tid] + bb1[tid];
  __syncthreads();

  {
    float acc = b2[tid];
    for (int k = 0; k < ND; ++k) acc += s.x1[k] * w2[tid * ND + k];
    s.hb[tid] = fmaxf(acc, 0.f);
  }
  __syncthreads();

  if (tid < ND) {
    float acc = b3[tid];
    for (int k = 0; k < NHID; ++k) acc += s.hb[k] * w3[tid * NHID + k];
    s.tvb[tid] = s.x1[tid] + acc;
  }
  __syncthreads();
  if (tid == 0) {
    float m = 0.f;
    for (int k = 0; k < ND; ++k) m += s.tvb[k];
    m *= (1.f / ND);
    float v = 0.f;
    for (int k = 0; k < ND; ++k) { float d = s.tvb[k] - m; v += d * d; }
    s.stats[0] = m;
    s.stats[1] = rsqrtf(v * (1.f / ND) + LN_EPS);
  }
  __syncthreads();
  if (tid < ND) {
    float o = (s.tvb[tid] - s.stats[0]) * s.stats[1] * g2[tid] + bb2[tid];
    xout[row * ND + tid] = o;  // FLOAT32 output
  }
}

// ---------------- K4: FUSED edge update (both stages) via MFMA -------------
// Per block (b,i), 12 tiles of 32 j-rows, all in LDS, no global scratch:
//   L1: (a_ij|a_ji)[32x128] @ W1ab^T  +  x_j[32x128] @ W1c^T  (both MFMA,
//       hi/lo split) + (x_i @ W1d^T + b1) [per-thread f32] -> relu -> H1
//   L2: H1 @ W2^T + a_ij -> LN1 -> t (f32 + hi/lo)
//   L3: t @ W3^T + b3 -> relu -> H2
//   L4: H2 @ W4^T + t + b4 -> LN2 -> out
// x_j staging and H2 alias the same 16KB LDS (live ranges disjoint,
// >=2 barriers apart). 56KB total -> 2 blocks/CU.
#define EMT 32
struct EFS {
  u16 Ahi[EMT][128];   // 8KB  row stride 256B, byte ^= (row&7)<<4
  u16 Alo[EMT][128];   // 8KB
  union {
    struct { u16 hi[EMT][128]; u16 lo[EMT][128]; } X;   // x_j (L1 only)
    struct { u16 hi[EMT][EH2]; u16 lo[EMT][EH2]; } H2;  // L3 out (L3/L4)
  } u;                 // 16KB
  u16 H1hi[EMT][NE];   // 4KB  row stride 128B
  u16 H1lo[EMT][NE];   // 4KB
  float Tf[EMT][NE];   // 8KB  f32 residual/LN buffer
  u16 T1hi[EMT][NE];   // 4KB
  u16 T1lo[EMT][NE];   // 4KB
};                     // 56KB

__global__ void __launch_bounds__(512) k_edge(
    const float* __restrict__ adj, const float* __restrict__ xq,
    const float* __restrict__ w1, const float* __restrict__ b1,
    const float* __restrict__ w2, const float* __restrict__ b2,
    const float* __restrict__ g1, const float* __restrict__ bb1,
    const float* __restrict__ w3, const float* __restrict__ b3,
    const float* __restrict__ w4, const float* __restrict__ b4,
    const float* __restrict__ g2, const float* __restrict__ bb2,
    float* __restrict__ adjout) {
  __shared__ EFS s;
  int bi = blockIdx.x;
  int b = bi / NN, i = bi % NN;
  int t = threadIdx.x;      // 512
  int w = t >> 6, l = t & 63;
  int m16 = (w & 1) * 16;
  int n16 = (w >> 1) * 16;
  int nb = (w >> 1) * 2;    // L3 n-frag pair base
  int lr = l & 15, lk = l >> 4;

  // per-wave weight fragments (f32 -> bf16 once per block)
  s16x8 B1a[4], B1c[4], B2[2], B3[2][2], B4[4];
  {
    const float* wr = w1 + (size_t)(n16 + lr) * EH1 + lk * 8;
#pragma unroll
    for (int ks = 0; ks < 4; ++ks) {
      B1a[ks] = cvt_frag(wr + ks * 32);        // K = a_ij|a_ji (cols 0..127)
      B1c[ks] = cvt_frag(wr + 128 + ks * 32);  // K = x_j (cols 128..255)
    }
    const float* w2r = w2 + (size_t)(n16 + lr) * NE + lk * 8;
#pragma unroll
    for (int ks = 0; ks < 2; ++ks) B2[ks] = cvt_frag(w2r + ks * 32);
#pragma unroll
    for (int n = 0; n < 2; ++n) {
      const float* w3r = w3 + (size_t)((nb + n) * 16 + lr) * NE + lk * 8;
#pragma unroll
      for (int ks = 0; ks < 2; ++ks) B3[n][ks] = cvt_frag(w3r + ks * 32);
    }
    const float* w4r = w4 + (size_t)(n16 + lr) * EH2 + lk * 8;
#pragma unroll
    for (int ks = 0; ks < 4; ++ks) B4[ks] = cvt_frag(w4r + ks * 32);
  }
  // x_i @ W1d^T (cols 256..383) for this thread's output col, f32 x bf16.
  float b1c;
  {
    float ci = 0.f;
    const float* xr = xq + (size_t)bi * ND;
    const float* wr = w1 + (size_t)(n16 + lr) * EH1 + 256;
#pragma unroll 4
    for (int k = 0; k < ND; ++k) ci += xr[k] * bfu(bfr(wr[k]));
    b1c = b1[n16 + lr] + ci;
  }
  float b2c = b2[n16 + lr];
  float b3c[2] = {b3[nb * 16 + lr], b3[(nb + 1) * 16 + lr]};
  float b4c = b4[n16 + lr];
  float g1l = g1[l], bl1 = bb1[l];
  float g2l = g2[l], bl2 = bb2[l];

  int arow = m16 + lr;
  int aswz = (arow & 7) << 4;

  for (int mt = 0; mt < NN / EMT; ++mt) {
    int jbase = mt * EMT;
    __syncthreads();  // protect LDS from previous tile's readers
    // ---- stage: A (a_ij | a_ji) + x_j, all hi/lo, 1024 16B units ----
    for (int p = t; p < EMT * 32; p += 512) {
      int row = p >> 5, uu = p & 31;
      if (uu < 16) {
        const float* src = (uu < 8)
            ? adj + ((size_t)bi * NN + jbase + row) * NE + uu * 8
            : adj + ((size_t)(b * NN + jbase + row) * NN + i) * NE + (uu - 8) * 8;
        uint4 hi, lo;
        cvt8_hl(src, hi, lo);
        int byt = (row * 256 + uu * 16) ^ ((row & 7) << 4);
        *(uint4*)((char*)s.Ahi + byt) = hi;
        *(uint4*)((char*)s.Alo + byt) = lo;
      } else {
        const float* src = xq + (size_t)(b * NN + jbase + row) * ND + (uu - 16) * 8;
        uint4 hi, lo;
        cvt8_hl(src, hi, lo);
        int byt = (row * 256 + (uu - 16) * 16) ^ ((row & 7) << 4);
        *(uint4*)((char*)s.u.X.hi + byt) = hi;
        *(uint4*)((char*)s.u.X.lo + byt) = lo;
      }
    }
    __syncthreads();

    // ---- L1: A @ W1ab^T + X @ W1c^T ----
    f32x4 acc = {0.f, 0.f, 0.f, 0.f};
#pragma unroll
    for (int ks = 0; ks < 4; ++ks) {
      int byt = (arow * 256 + ks * 64 + lk * 16) ^ aswz;
      s16x8 ah = *(const s16x8*)((const char*)s.Ahi + byt);
      s16x8 al = *(const s16x8*)((const char*)s.Alo + byt);
      acc = MFMA16(ah, B1a[ks], acc);
      acc = MFMA16(al, B1a[ks], acc);
      s16x8 xh = *(const s16x8*)((const char*)s.u.X.hi + byt);
      s16x8 xl = *(const s16x8*)((const char*)s.u.X.lo + byt);
      acc = MFMA16(xh, B1c[ks], acc);
      acc = MFMA16(xl, B1c[ks], acc);
    }
#pragma unroll
    for (int r = 0; r < 4; ++r) {
      int row = m16 + lk * 4 + r;
      float hv = fmaxf(acc[r] + b1c, 0.f);
      u16 hh = bfr(hv);
      u16 hl = bfr(hv - bfu(hh));
      int byt = (row * 128 + (n16 + lr) * 2) ^ ((row & 7) << 4);
      *(u16*)((char*)s.H1hi + byt) = hh;
      *(u16*)((char*)s.H1lo + byt) = hl;
    }
    __syncthreads();

    // ---- L2: H1 @ W2^T + a_ij -> Tf ----
    f32x4 acc2 = {0.f, 0.f, 0.f, 0.f};
#pragma unroll
    for (int ks = 0; ks < 2; ++ks) {
      int byt = (arow * 128 + ks * 64 + lk * 16) ^ aswz;
      s16x8 ah = *(const s16x8*)((const char*)s.H1hi + byt);
      s16x8 al = *(const s16x8*)((const char*)s.H1lo + byt);
      acc2 = MFMA16(ah, B2[ks], acc2);
      acc2 = MFMA16(al, B2[ks], acc2);
    }
#pragma unroll
    for (int r = 0; r < 4; ++r) {
      int row = m16 + lk * 4 + r;
      int col = n16 + lr;
      int abyt = (row * 256 + col * 2) ^ ((row & 7) << 4);
      float aorig = bfu(*(const u16*)((const char*)s.Ahi + abyt)) +
                    bfu(*(const u16*)((const char*)s.Alo + abyt));
      s.Tf[row][col] = aorig + acc2[r] + b2c;
    }
    __syncthreads();

    // ---- LN1 (wave w -> 4 rows, lane = col); emit t f32 + hi/lo ----
#pragma unroll
    for (int rr = 0; rr < EMT / 8; ++rr) {
      int row = w * (EMT / 8) + rr;
      float tv = s.Tf[row][l];
      float mean = wsum64(tv) * (1.f / NE);
      float dv = tv - mean;
      float var = wsum64(dv * dv) * (1.f / NE);
      float o = dv * rsqrtf(var + LN_EPS) * g1l + bl1;
      s.Tf[row][l] = o;
      u16 oh = bfr(o);
      u16 ol = bfr(o - bfu(oh));
      int byt = (row * 128 + l * 2) ^ ((row & 7) << 4);
      *(u16*)((char*)s.T1hi + byt) = oh;
      *(u16*)((char*)s.T1lo + byt) = ol;
    }
    __syncthreads();

    // ---- L3: t @ W3^T -> relu -> H2 [32x128] (H2 aliases X, X is dead) ----
    f32x4 a3[2] = {{0.f, 0.f, 0.f, 0.f}, {0.f, 0.f, 0.f, 0.f}};
#pragma unroll
    for (int ks = 0; ks < 2; ++ks) {
      int byt = (arow * 128 + ks * 64 + lk * 16) ^ aswz;
      s16x8 ah = *(const s16x8*)((const char*)s.T1hi + byt);
      s16x8 al = *(const s16x8*)((const char*)s.T1lo + byt);
#pragma unroll
      for (int n = 0; n < 2; ++n) {
        a3[n] = MFMA16(ah, B3[n][ks], a3[n]);
        a3[n] = MFMA16(al, B3[n][ks], a3[n]);
      }
    }
#pragma unroll
    for (int n = 0; n < 2; ++n) {
#pragma unroll
      for (int r = 0; r < 4; ++r) {
        float hv = fmaxf(a3[n][r] + b3c[n], 0.f);
        u16 hh = bfr(hv);
        u16 hl = bfr(hv - bfu(hh));
        int row = m16 + lk * 4 + r;
        int byt = (row * 256 + ((nb + n) * 16 + lr) * 2) ^ ((row & 7) << 4);
        *(u16*)((char*)s.u.H2.hi + byt) = hh;
        *(u16*)((char*)s.u.H2.lo + byt) = hl;
      }
    }
    __syncthreads();

    // ---- L4: H2 @ W4^T + t -> Tf ----
    f32x4 a4 = {0.f, 0.f, 0.f, 0.f};
#pragma unroll
    for (int ks = 0; ks < 4; ++ks) {
      int byt = (arow * 256 + ks * 64 + lk * 16) ^ aswz;
      s16x8 ah = *(const s16x8*)((const char*)s.u.H2.hi + byt);
      s16x8 al = *(const s16x8*)((const char*)s.u.H2.lo + byt);
      a4 = MFMA16(ah, B4[ks], a4);
      a4 = MFMA16(al, B4[ks], a4);
    }
#pragma unroll
    for (int r = 0; r < 4; ++r) {
      int row = m16 + lk * 4 + r;
      int col = n16 + lr;
      s.Tf[row][col] = s.Tf[row][col] + a4[r] + b4c;  // same-slot RMW
    }
    __syncthreads();

    // ---- LN2 + store ----
#pragma unroll
    for (int rr = 0; rr < EMT / 8; ++rr) {
      int row = w * (EMT / 8) + rr;
      float tv = s.Tf[row][l];
      float mean = wsum64(tv) * (1.f / NE);
      float dv = tv - mean;
      float var = wsum64(dv * dv) * (1.f / NE);
      float o = dv * rsqrtf(var + LN_EPS) * g2l + bl2;
      adjout[((size_t)bi * NN + jbase + row) * NE + l] = o;
    }
  }
}

extern "C" void kernel_launch(void* const* d_in, const int* in_sizes, int n_in,
                              void* d_out, int out_size, void* d_ws, size_t ws_size,
                              hipStream_t stream) {
  (void)in_sizes; (void)n_in; (void)out_size; (void)d_ws; (void)ws_size;
  const float* x      = (const float*)d_in[0];
  const float* adj    = (const float*)d_in[1];
  const float* wnq    = (const float*)d_in[2];
  const float* wnk    = (const float*)d_in[3];
  const float* wnv    = (const float*)d_in[4];
  const float* weq    = (const float*)d_in[5];
  const float* wek    = (const float*)d_in[6];
  const float* wev    = (const float*)d_in[7];
  const float* nfc1_w = (const float*)d_in[8];
  const float* nfc1_b = (const float*)d_in[9];
  const float* ln1_g  = (const float*)d_in[10];
  const float* ln1_b  = (const float*)d_in[11];
  const float* nfc2_w = (const float*)d_in[12];
  const float* nfc2_b = (const float*)d_in[13];
  const float* nfc3_w = (const float*)d_in[14];
  const float* nfc3_b = (const float*)d_in[15];
  const float* ln2_g  = (const float*)d_in[16];
  const float* ln2_b  = (const float*)d_in[17];
  const float* efc1_w = (const float*)d_in[18];
  const float* efc1_b = (const float*)d_in[19];
  const float* efc2_w = (const float*)d_in[20];
  const float* efc2_b = (const float*)d_in[21];
  const float* eln1_g = (const float*)d_in[22];
  const float* eln1_b = (const float*)d_in[23];
  const float* efc3_w = (const float*)d_in[24];
  const float* efc3_b = (const float*)d_in[25];
  const float* efc4_w = (const float*)d_in[26];
  const float* efc4_b = (const float*)d_in[27];
  const float* eln2_g = (const float*)d_in[28];
  const float* eln2_b = (const float*)d_in[29];

  float* outf = (float*)d_out;          // FLOAT32 output buffer: [x ; adj]
  float* outadj = outf + XOUT_ELEMS;

  // f32 scratch in the tail of the adj-output region (dead until k_edge).
  float* scratch = outf + OUT_ELEMS - SCRATCH_F32;
  float* nq  = scratch;
  float* nk  = scratch + XOUT_ELEMS;
  float* nv  = scratch + 2 * XOUT_ELEMS;
  float* att = scratch + 3 * XOUT_ELEMS;

  k_node_qkv<<<NB * NN, 128, 0, stream>>>(x, wnq, wnk, wnv, nq, nk, nv);
  k_attn<<<NB * NN, 512, 0, stream>>>(adj, weq, wek, wev, nq, nk, nv, att);
  k_node_ffn<<<NB * NN, 256, 0, stream>>>(x, att, nfc1_w, nfc1_b, ln1_g, ln1_b,
                                          nfc2_w, nfc2_b, nfc3_w, nfc3_b,
                                          ln2_g, ln2_b, outf);
  k_edge<<<NB * NN, 512, 0, stream>>>(adj, outf, efc1_w, efc1_b,
                                      efc2_w, efc2_b, eln1_g, eln1_b,
                                      efc3_w, efc3_b, efc4_w, efc4_b,
                                      eln2_g, eln2_b, outadj);
}

// Round 6
// 570.280 us; speedup vs baseline: 1.2694x; 1.2694x over previous
//
#include <hip/hip_runtime.h>
#include <hip/hip_bf16.h>

typedef unsigned short u16;
typedef unsigned int u32;

#define NB 2
#define NN 384
#define ND 128
#define NE 64
#define NHD 8
#define NHID 256
#define EH1 384
#define EH2 128
#define LN_EPS 1e-5f
#define ATT_SCALE 0.17677669529663687f  // 1/sqrt(NODE_HIDDEN//HEADS)=1/sqrt(32)

#define XOUT_ELEMS (NB * NN * ND)                 // 98304
#define ADJ_ELEMS ((size_t)NB * NN * NN * NE)     // 18874368
#define OUT_ELEMS (XOUT_ELEMS + ADJ_ELEMS)        // 18972672 f32 elements
// f32 scratch carved from the TAIL of the adj-output region (dead until
// k_edge1 writes it, by which time scratch is fully consumed). No d_ws.
#define SCRATCH_F32 (4 * XOUT_ELEMS)              // nq,nk,nv,att

typedef __attribute__((ext_vector_type(4))) float f32x4;
typedef __attribute__((ext_vector_type(8))) short s16x8;
#define MFMA16(a, b, c) __builtin_amdgcn_mfma_f32_16x16x32_bf16(a, b, c, 0, 0, 0)

__device__ __forceinline__ float bflo(u32 u) {
  return __builtin_bit_cast(float, u << 16);
}
__device__ __forceinline__ float bfhi(u32 u) {
  return __builtin_bit_cast(float, u & 0xffff0000u);
}
__device__ __forceinline__ u16 bfr(float f) {
  return __builtin_bit_cast(u16, __float2bfloat16(f));
}
__device__ __forceinline__ float bfu(u16 h) {
  return __builtin_bit_cast(float, ((u32)h) << 16);
}
__device__ __forceinline__ u32 packbf(float a, float b) {
  return (u32)bfr(a) | ((u32)bfr(b) << 16);
}
__device__ __forceinline__ float wsum64(float v) {
#pragma unroll
  for (int o = 32; o > 0; o >>= 1) v += __shfl_xor(v, o, 64);
  return v;
}
__device__ __forceinline__ float wmax64(float v) {
#pragma unroll
  for (int o = 32; o > 0; o >>= 1) v = fmaxf(v, __shfl_xor(v, o, 64));
  return v;
}

// convert 8 consecutive f32 -> one bf16 weight fragment (short8)
__device__ __forceinline__ s16x8 cvt_frag(const float* p) {
  float4 a = *(const float4*)p;
  float4 c = *(const float4*)(p + 4);
  s16x8 r;
  r[0] = (short)bfr(a.x); r[1] = (short)bfr(a.y);
  r[2] = (short)bfr(a.z); r[3] = (short)bfr(a.w);
  r[4] = (short)bfr(c.x); r[5] = (short)bfr(c.y);
  r[6] = (short)bfr(c.z); r[7] = (short)bfr(c.w);
  return r;
}

// convert 8 consecutive f32 -> hi/lo bf16 pairs (16B each)
__device__ __forceinline__ void cvt8_hl(const float* p, uint4& hi, uint4& lo) {
  float4 a = *(const float4*)p;
  float4 c = *(const float4*)(p + 4);
  float v[8] = {a.x, a.y, a.z, a.w, c.x, c.y, c.z, c.w};
  u32 hw[4], lw[4];
#pragma unroll
  for (int e = 0; e < 4; ++e) {
    u16 h0 = bfr(v[2 * e]), h1 = bfr(v[2 * e + 1]);
    u16 l0 = bfr(v[2 * e] - bfu(h0));
    u16 l1 = bfr(v[2 * e + 1] - bfu(h1));
    hw[e] = (u32)h0 | ((u32)h1 << 16);
    lw[e] = (u32)l0 | ((u32)l1 << 16);
  }
  hi.x = hw[0]; hi.y = hw[1]; hi.z = hw[2]; hi.w = hw[3];
  lo.x = lw[0]; lo.y = lw[1]; lo.z = lw[2]; lo.w = lw[3];
}

// ---------------- K1: nq/nk/nv = x @ w{q,k,v}.T (f32, plain) ----------------
__global__ void k_node_qkv(const float* __restrict__ x,
                           const float* __restrict__ wq,
                           const float* __restrict__ wk,
                           const float* __restrict__ wv,
                           float* __restrict__ nq, float* __restrict__ nk,
                           float* __restrict__ nv) {
  int row = blockIdx.x;  // b*N+i
  int t = threadIdx.x;   // 128
  __shared__ float xs[ND];
  xs[t] = x[row * ND + t];
  __syncthreads();
  float aq = 0.f, ak = 0.f, av = 0.f;
  for (int k = 0; k < ND; ++k) {
    float xv = xs[k];
    aq += xv * wq[t * ND + k];
    ak += xv * wk[t * ND + k];
    av += xv * wv[t * ND + k];
  }
  nq[row * ND + t] = aq;
  nk[row * ND + t] = ak;
  nv[row * ND + t] = av;
}

// ---------------- K2: attention via MFMA edge projections ----------------
#define ATJ 128
struct AttnS {
  u16 Ahi[ATJ][NE];     // 16KB, row stride 128B, byte ^= (row&7)<<4
  u16 Alo[ATJ][NE];     // 16KB
  float sc[NHD][NN];    // 12KB scores -> probs
  float psum[NHD][NE];  // 2KB
  float part[4][ND];    // 2KB epilogue partials
};

__global__ void __launch_bounds__(512) k_attn(
    const float* __restrict__ adj,
    const float* __restrict__ weq,
    const float* __restrict__ wek,
    const float* __restrict__ wev,
    const float* __restrict__ nq,
    const float* __restrict__ nk,
    const float* __restrict__ nv,
    float* __restrict__ att) {
  __shared__ AttnS s;
  int bi = blockIdx.x;     // b*N + i
  int b = bi / NN;
  int t = threadIdx.x;     // 512
  int h = t >> 6;          // wave = head
  int l = t & 63;
  int lr = l & 15, lk = l >> 4;

  s16x8 BQ[2], BK[2];
  {
    const float* wqp = weq + (size_t)(h * 16 + lr) * NE + lk * 8;
    const float* wkp = wek + (size_t)(h * 16 + lr) * NE + lk * 8;
    BQ[0] = cvt_frag(wqp); BQ[1] = cvt_frag(wqp + 32);
    BK[0] = cvt_frag(wkp); BK[1] = cvt_frag(wkp + 32);
  }
  float nqd = nq[(size_t)bi * ND + h * 16 + lr];

  // ---------------- pass 1: scores ----------------
  for (int tile = 0; tile < NN / ATJ; ++tile) {
    int jbase = tile * ATJ;
    __syncthreads();
    for (int p = t; p < ATJ * 8; p += 512) {
      int row = p >> 3, u = p & 7;
      const float* src = adj + ((size_t)bi * NN + jbase + row) * NE + u * 8;
      uint4 hi, lo;
      cvt8_hl(src, hi, lo);
      int byt = (row * 128 + u * 16) ^ ((row & 7) << 4);
      *(uint4*)((char*)s.Ahi + byt) = hi;
      *(uint4*)((char*)s.Alo + byt) = lo;
    }
    __syncthreads();

#pragma unroll
    for (int sub = 0; sub < ATJ / 16; ++sub) {
      int trow = sub * 16 + lr;
      int swz = (trow & 7) << 4;
      f32x4 eq = {0.f, 0.f, 0.f, 0.f}, ek = {0.f, 0.f, 0.f, 0.f};
#pragma unroll
      for (int ks = 0; ks < 2; ++ks) {
        int byt = (trow * 128 + ks * 64 + lk * 16) ^ swz;
        s16x8 ah = *(const s16x8*)((const char*)s.Ahi + byt);
        s16x8 al = *(const s16x8*)((const char*)s.Alo + byt);
        eq = MFMA16(ah, BQ[ks], eq);
        eq = MFMA16(al, BQ[ks], eq);
        ek = MFMA16(ah, BK[ks], ek);
        ek = MFMA16(al, BK[ks], ek);
      }
#pragma unroll
      for (int r = 0; r < 4; ++r) {
        int j = jbase + sub * 16 + lk * 4 + r;
        float kv = nk[((size_t)b * NN + j) * ND + h * 16 + lr] + ek[r];
        float prod = (nqd + eq[r]) * kv;
#pragma unroll
        for (int o = 8; o > 0; o >>= 1) prod += __shfl_xor(prod, o, 64);
        if (lr == 0) s.sc[h][j] = prod * ATT_SCALE;
      }
    }
  }
  __syncthreads();

  // ---------------- softmax: wave h owns row h ----------------
  {
    float vals[NN / 64];
    float m = -1e30f;
#pragma unroll
    for (int r = 0; r < NN / 64; ++r) {
      vals[r] = s.sc[h][l + 64 * r];
      m = fmaxf(m, vals[r]);
    }
    m = wmax64(m);
    float sum = 0.f;
#pragma unroll
    for (int r = 0; r < NN / 64; ++r) {
      vals[r] = __expf(vals[r] - m);
      sum += vals[r];
    }
    sum = wsum64(sum);
    float rinv = 1.f / sum;
#pragma unroll
    for (int r = 0; r < NN / 64; ++r) s.sc[h][l + 64 * r] = vals[r] * rinv;
  }

  // ---------------- pass 2: psum[h][k=l] = sum_j p * adj[j][k] -------------
  {
    float pacc = 0.f;
    const float* ab = adj + (size_t)bi * NN * NE + l;
    const float* prow = s.sc[h];
#pragma unroll 4
    for (int j = 0; j < NN; ++j) pacc += prow[j] * ab[(size_t)j * NE];
    s.psum[h][l] = pacc;
  }
  __syncthreads();

  // ---------------- epilogue: att = sum_j p nv_j + Ve psum ----------------
  {
    int c = t & 127, grp = t >> 7;  // 4-way j-split
    int hc = c >> 4;
    float acc = 0.f;
    const float* nvb = nv + (size_t)b * NN * ND + c;
    const float* pr = s.sc[hc];
#pragma unroll 4
    for (int j = grp * (NN / 4); j < (grp + 1) * (NN / 4); ++j)
      acc += pr[j] * nvb[(size_t)j * ND];
    s.part[grp][c] = acc;
  }
  __syncthreads();
  if (t < ND) {
    int c = t, hc = c >> 4;
    float acc = s.part[0][c] + s.part[1][c] + s.part[2][c] + s.part[3][c];
    const float4* wr = (const float4*)(wev + c * NE);
    const float* ps = s.psum[hc];
#pragma unroll
    for (int k4 = 0; k4 < NE / 4; ++k4) {
      float4 w4 = wr[k4];
      acc += w4.x * ps[4 * k4] + w4.y * ps[4 * k4 + 1] +
             w4.z * ps[4 * k4 + 2] + w4.w * ps[4 * k4 + 3];
    }
    att[(size_t)bi * ND + (c & 15) * NHD + hc] = acc;
  }
}

// ---------------- K3: nfc1 + LN1 + FFN + LN2, wave-parallel LNs ------------
struct FfnS {
  float atts[ND];
  float tvb[ND];
  float x1[ND];
  float hb[NHID];
  float stats[2];  // mean, rstd
};

__global__ void k_node_ffn(const float* __restrict__ x,
                           const float* __restrict__ att,
                           const float* __restrict__ w1, const float* __restrict__ b1,
                           const float* __restrict__ g1, const float* __restrict__ bb1,
                           const float* __restrict__ w2, const float* __restrict__ b2,
                           const float* __restrict__ w3, const float* __restrict__ b3,
                           const float* __restrict__ g2, const float* __restrict__ bb2,
                           float* __restrict__ xout) {
  __shared__ FfnS s;
  int row = blockIdx.x;
  int tid = threadIdx.x;  // 256
  if (tid < ND) s.atts[tid] = att[row * ND + tid];
  __syncthreads();

  if (tid < ND) {
    float acc = b1[tid];
    for (int k = 0; k < ND; ++k) acc += s.atts[k] * w1[tid * ND + k];
    s.tvb[tid] = x[row * ND + tid] + acc;
  }
  __syncthreads();
  if (tid < 64) {  // wave 0: LN1 stats over 128 via shuffle reduce
    float v0 = s.tvb[tid], v1 = s.tvb[tid + 64];
    float m = wsum64(v0 + v1) * (1.f / ND);
    float d0 = v0 - m, d1 = v1 - m;
    float var = wsum64(d0 * d0 + d1 * d1) * (1.f / ND);
    if (tid == 0) {
      s.stats[0] = m;
      s.stats[1] = rsqrtf(var + LN_EPS);
    }
  }
  __syncthreads();
  if (tid < ND)
    s.x1[tid] = (s.tvb[tid] - s.stats[0]) * s.stats[1] * g1[tid] + bb1[tid];
  __syncthreads();

  {
    float acc = b2[tid];
    for (int k = 0; k < ND; ++k) acc += s.x1[k] * w2[tid * ND + k];
    s.hb[tid] = fmaxf(acc, 0.f);
  }
  __syncthreads();

  if (tid < ND) {
    float acc = b3[tid];
    for (int k = 0; k < NHID; ++k) acc += s.hb[k] * w3[tid * NHID + k];
    s.tvb[tid] = s.x1[tid] + acc;
  }
  __syncthreads();
  if (tid < 64) {  // wave 0: LN2 stats
    float v0 = s.tvb[tid], v1 = s.tvb[tid + 64];
    float m = wsum64(v0 + v1) * (1.f / ND);
    float d0 = v0 - m, d1 = v1 - m;
    float var = wsum64(d0 * d0 + d1 * d1) * (1.f / ND);
    if (tid == 0) {
      s.stats[0] = m;
      s.stats[1] = rsqrtf(var + LN_EPS);
    }
  }
  __syncthreads();
  if (tid < ND) {
    float o = (s.tvb[tid] - s.stats[0]) * s.stats[1] * g2[tid] + bb2[tid];
    xout[row * ND + tid] = o;  // FLOAT32 output
  }
}

// ---------------- K4: edge stage 1 via MFMA, factored node projections -----
// Per block (b,i), 12 M-tiles of 32 j-rows:
//   L1: [32x256](a_ij|a_ji|x_j) @ W1abc^T (MFMA, hi/lo split)
//       + (x_i @ W1d^T + b1) [per-thread f32xbf16] -> relu -> H1
//   L2: H1 @ W2^T + a_ij ; residual + LN over 64 cols.
// Same barrier/swizzle structure as the R3-proven kernel; only K shrinks
// 384->256 (staging 1536->1024 units, L1 MFMAs 24->16). LDS 40KB.
#define EMT 32

struct E1M {
  u16 Ahi[EMT][256];   // 16KB swizzled, row stride 512B
  u16 Alo[EMT][256];   // 16KB
  u16 Hhi[EMT][NE];    // 4KB swizzled, row stride 128B
  u16 Hlo[EMT][NE];    // 4KB ; Hhi+Hlo reused as f32 tvb[32][64] for LN
};

__global__ void __launch_bounds__(512) k_edge1(
    const float* __restrict__ adj, const float* __restrict__ xq,
    const float* __restrict__ w1, const float* __restrict__ b1,
    const float* __restrict__ w2, const float* __restrict__ b2,
    const float* __restrict__ g, const float* __restrict__ bb,
    float* __restrict__ adj1out) {
  __shared__ E1M s;
  int bi = blockIdx.x;
  int b = bi / NN, i = bi % NN;
  int t = threadIdx.x;      // 512
  int w = t >> 6, l = t & 63;
  int m16 = (w & 1) * 16;   // wave's M sub-tile base
  int n16 = (w >> 1) * 16;  // wave's N sub-tile base
  int lr = l & 15, lk = l >> 4;

  // per-wave weight fragments (f32 -> bf16 once per block), cols 0..255
  s16x8 B1[8], B2[2];
  {
    const float* wr = w1 + (size_t)(n16 + lr) * EH1 + lk * 8;
#pragma unroll
    for (int ks = 0; ks < 8; ++ks) B1[ks] = cvt_frag(wr + ks * 32);
    const float* w2r = w2 + (size_t)(n16 + lr) * NE + lk * 8;
#pragma unroll
    for (int ks = 0; ks < 2; ++ks) B2[ks] = cvt_frag(w2r + ks * 32);
  }
  // x_i @ W1d^T (cols 256..383), f32 activation x bf16 weight (exact-act).
  float bias1;
  {
    float ci = 0.f;
    const float* xr = xq + (size_t)bi * ND;
    const float* wr = w1 + (size_t)(n16 + lr) * EH1 + 256;
#pragma unroll 4
    for (int k = 0; k < ND; ++k) ci += xr[k] * bfu(bfr(wr[k]));
    bias1 = b1[n16 + lr] + ci;
  }
  float bias2 = b2[n16 + lr];
  float gl = g[l], bl = bb[l];

  for (int mt = 0; mt < NN / EMT; ++mt) {
    int jbase = mt * EMT;
    __syncthreads();
    // stage tile: 32 rows x 32 x 16B units (a_ij 8 | a_ji 8 | x_j 16), hi/lo
    for (int p = t; p < EMT * 32; p += 512) {
      int row = p >> 5, uu = p & 31;
      const float* src;
      if (uu < 8)
        src = adj + ((size_t)bi * NN + jbase + row) * NE + uu * 8;
      else if (uu < 16)
        src = adj + ((size_t)(b * NN + jbase + row) * NN + i) * NE + (uu - 8) * 8;
      else
        src = xq + (size_t)(b * NN + jbase + row) * ND + (uu - 16) * 8;
      uint4 hi, lo;
      cvt8_hl(src, hi, lo);
      int byt = (row * 512 + uu * 16) ^ ((row & 7) << 4);
      *(uint4*)((char*)s.Ahi + byt) = hi;
      *(uint4*)((char*)s.Alo + byt) = lo;
    }
    __syncthreads();

    // layer1: K=256
    f32x4 acc = {0.f, 0.f, 0.f, 0.f};
    int arow = m16 + lr;
    int aswz = (arow & 7) << 4;
#pragma unroll
    for (int ks = 0; ks < 8; ++ks) {
      int byt = (arow * 512 + ks * 64 + lk * 16) ^ aswz;
      s16x8 ah = *(const s16x8*)((const char*)s.Ahi + byt);
      s16x8 al = *(const s16x8*)((const char*)s.Alo + byt);
      acc = MFMA16(ah, B1[ks], acc);
      acc = MFMA16(al, B1[ks], acc);
    }
#pragma unroll
    for (int r = 0; r < 4; ++r) {
      float hv = fmaxf(acc[r] + bias1, 0.f);
      u16 hh = bfr(hv);
      u16 hl = bfr(hv - bfu(hh));
      int row = m16 + lk * 4 + r;
      int byt = (row * 128 + (n16 + lr) * 2) ^ ((row & 7) << 4);
      *(u16*)((char*)s.Hhi + byt) = hh;
      *(u16*)((char*)s.Hlo + byt) = hl;
    }
    __syncthreads();

    // layer2
    f32x4 acc2 = {0.f, 0.f, 0.f, 0.f};
#pragma unroll
    for (int ks = 0; ks < 2; ++ks) {
      int byt = (arow * 128 + ks * 64 + lk * 16) ^ aswz;
      s16x8 ah = *(const s16x8*)((const char*)s.Hhi + byt);
      s16x8 al = *(const s16x8*)((const char*)s.Hlo + byt);
      acc2 = MFMA16(ah, B2[ks], acc2);
      acc2 = MFMA16(al, B2[ks], acc2);
    }
    __syncthreads();  // H reads done -> reuse as f32 tv buffer
    float* tvb = (float*)s.Hhi;
#pragma unroll
    for (int r = 0; r < 4; ++r) {
      int row = m16 + lk * 4 + r;
      int col = n16 + lr;
      int abyt = (row * 512 + col * 2) ^ ((row & 7) << 4);
      float aorig = bfu(*(const u16*)((const char*)s.Ahi + abyt)) +
                    bfu(*(const u16*)((const char*)s.Alo + abyt));
      tvb[row * NE + col] = aorig + acc2[r] + bias2;
    }
    __syncthreads();
    // LN: wave w handles rows w*4..w*4+3, lane = col
#pragma unroll
    for (int rr = 0; rr < EMT / 8; ++rr) {
      int row = w * (EMT / 8) + rr;
      float tv = tvb[row * NE + l];
      float mean = wsum64(tv) * (1.f / NE);
      float dv = tv - mean;
      float var = wsum64(dv * dv) * (1.f / NE);
      float o = dv * rsqrtf(var + LN_EPS) * gl + bl;
      adj1out[((size_t)bi * NN + jbase + row) * NE + l] = o;
    }
  }
}

// ---------------- K5: edge stage 2 via MFMA (in-place on d_out adj) --------
struct E2M {
  u16 Ahi[EMT][NE];    // 4KB swizzled, row stride 128B
  u16 Alo[EMT][NE];    // 4KB
  u16 Hhi[EMT][EH2];   // 8KB swizzled, row stride 256B ; reused as f32 tvb
  u16 Hlo[EMT][EH2];   // 8KB
};

__global__ void __launch_bounds__(512) k_edge2(
    float* __restrict__ adjio,
    const float* __restrict__ w3, const float* __restrict__ b3,
    const float* __restrict__ w4, const float* __restrict__ b4,
    const float* __restrict__ g, const float* __restrict__ bb) {
  __shared__ E2M s;
  int bi = blockIdx.x;
  int t = threadIdx.x;      // 512
  int w = t >> 6, l = t & 63;
  int m16 = (w & 1) * 16;
  int nb = (w >> 1) * 2;    // layer3 n16 pair base (0,2,4,6)
  int n16 = (w >> 1) * 16;  // layer4 col base
  int lr = l & 15, lk = l >> 4;

  s16x8 B3[2][2], B4[4];
  {
#pragma unroll
    for (int n = 0; n < 2; ++n) {
      const float* wr = w3 + (size_t)((nb + n) * 16 + lr) * NE + lk * 8;
#pragma unroll
      for (int ks = 0; ks < 2; ++ks) B3[n][ks] = cvt_frag(wr + ks * 32);
    }
    const float* w4r = w4 + (size_t)(n16 + lr) * EH2 + lk * 8;
#pragma unroll
    for (int ks = 0; ks < 4; ++ks) B4[ks] = cvt_frag(w4r + ks * 32);
  }
  float bias3[2] = {b3[nb * 16 + lr], b3[(nb + 1) * 16 + lr]};
  float bias4 = b4[n16 + lr];
  float gl = g[l], bl = bb[l];

  for (int mt = 0; mt < NN / EMT; ++mt) {
    int jbase = mt * EMT;
    __syncthreads();
    for (int p = t; p < EMT * 8; p += 512) {  // 256 units, threads<256 active
      int row = p >> 3, u = p & 7;
      const float* src = adjio + ((size_t)bi * NN + jbase + row) * NE + u * 8;
      uint4 hi, lo;
      cvt8_hl(src, hi, lo);
      int byt = (row * 128 + u * 16) ^ ((row & 7) << 4);
      *(uint4*)((char*)s.Ahi + byt) = hi;
      *(uint4*)((char*)s.Alo + byt) = lo;
    }
    __syncthreads();

    // layer3: out [32 x 128]
    f32x4 a3[2] = {{0.f, 0.f, 0.f, 0.f}, {0.f, 0.f, 0.f, 0.f}};
    int arow = m16 + lr;
    int aswz = (arow & 7) << 4;
#pragma unroll
    for (int ks = 0; ks < 2; ++ks) {
      int byt = (arow * 128 + ks * 64 + lk * 16) ^ aswz;
      s16x8 ah = *(const s16x8*)((const char*)s.Ahi + byt);
      s16x8 al = *(const s16x8*)((const char*)s.Alo + byt);
#pragma unroll
      for (int n = 0; n < 2; ++n) {
        a3[n] = MFMA16(ah, B3[n][ks], a3[n]);
        a3[n] = MFMA16(al, B3[n][ks], a3[n]);
      }
    }
#pragma unroll
    for (int n = 0; n < 2; ++n) {
#pragma unroll
      for (int r = 0; r < 4; ++r) {
        float hv = fmaxf(a3[n][r] + bias3[n], 0.f);
        u16 hh = bfr(hv);
        u16 hl = bfr(hv - bfu(hh));
        int row = m16 + lk * 4 + r;
        int byt = (row * 256 + ((nb + n) * 16 + lr) * 2) ^ ((row & 7) << 4);
        *(u16*)((char*)s.Hhi + byt) = hh;
        *(u16*)((char*)s.Hlo + byt) = hl;
      }
    }
    __syncthreads();

    // layer4: out [32 x 64]
    f32x4 a4 = {0.f, 0.f, 0.f, 0.f};
#pragma unroll
    for (int ks = 0; ks < 4; ++ks) {
      int byt = (arow * 256 + ks * 64 + lk * 16) ^ aswz;
      s16x8 ah = *(const s16x8*)((const char*)s.Hhi + byt);
      s16x8 al = *(const s16x8*)((const char*)s.Hlo + byt);
      a4 = MFMA16(ah, B4[ks], a4);
      a4 = MFMA16(al, B4[ks], a4);
    }
    __syncthreads();  // H reads done -> reuse as f32 tv buffer
    float* tvb = (float*)s.Hhi;
#pragma unroll
    for (int r = 0; r < 4; ++r) {
      int row = m16 + lk * 4 + r;
      int col = n16 + lr;
      int abyt = (row * 128 + col * 2) ^ ((row & 7) << 4);
      float aorig = bfu(*(const u16*)((const char*)s.Ahi + abyt)) +
                    bfu(*(const u16*)((const char*)s.Alo + abyt));
      tvb[row * NE + col] = aorig + a4[r] + bias4;
    }
    __syncthreads();
#pragma unroll
    for (int rr = 0; rr < EMT / 8; ++rr) {
      int row = w * (EMT / 8) + rr;
      float tv = tvb[row * NE + l];
      float mean = wsum64(tv) * (1.f / NE);
      float dv = tv - mean;
      float var = wsum64(dv * dv) * (1.f / NE);
      float o = dv * rsqrtf(var + LN_EPS) * gl + bl;
      adjio[((size_t)bi * NN + jbase + row) * NE + l] = o;
    }
  }
}

extern "C" void kernel_launch(void* const* d_in, const int* in_sizes, int n_in,
                              void* d_out, int out_size, void* d_ws, size_t ws_size,
                              hipStream_t stream) {
  (void)in_sizes; (void)n_in; (void)out_size; (void)d_ws; (void)ws_size;
  const float* x      = (const float*)d_in[0];
  const float* adj    = (const float*)d_in[1];
  const float* wnq    = (const float*)d_in[2];
  const float* wnk    = (const float*)d_in[3];
  const float* wnv    = (const float*)d_in[4];
  const float* weq    = (const float*)d_in[5];
  const float* wek    = (const float*)d_in[6];
  const float* wev    = (const float*)d_in[7];
  const float* nfc1_w = (const float*)d_in[8];
  const float* nfc1_b = (const float*)d_in[9];
  const float* ln1_g  = (const float*)d_in[10];
  const float* ln1_b  = (const float*)d_in[11];
  const float* nfc2_w = (const float*)d_in[12];
  const float* nfc2_b = (const float*)d_in[13];
  const float* nfc3_w = (const float*)d_in[14];
  const float* nfc3_b = (const float*)d_in[15];
  const float* ln2_g  = (const float*)d_in[16];
  const float* ln2_b  = (const float*)d_in[17];
  const float* efc1_w = (const float*)d_in[18];
  const float* efc1_b = (const float*)d_in[19];
  const float* efc2_w = (const float*)d_in[20];
  const float* efc2_b = (const float*)d_in[21];
  const float* eln1_g = (const float*)d_in[22];
  const float* eln1_b = (const float*)d_in[23];
  const float* efc3_w = (const float*)d_in[24];
  const float* efc3_b = (const float*)d_in[25];
  const float* efc4_w = (const float*)d_in[26];
  const float* efc4_b = (const float*)d_in[27];
  const float* eln2_g = (const float*)d_in[28];
  const float* eln2_b = (const float*)d_in[29];

  float* outf = (float*)d_out;          // FLOAT32 output buffer: [x ; adj]
  float* outadj = outf + XOUT_ELEMS;

  // f32 scratch in the tail of the adj-output region (dead until k_edge1).
  float* scratch = outf + OUT_ELEMS - SCRATCH_F32;
  float* nq  = scratch;
  float* nk  = scratch + XOUT_ELEMS;
  float* nv  = scratch + 2 * XOUT_ELEMS;
  float* att = scratch + 3 * XOUT_ELEMS;

  k_node_qkv<<<NB * NN, 128, 0, stream>>>(x, wnq, wnk, wnv, nq, nk, nv);
  k_attn<<<NB * NN, 512, 0, stream>>>(adj, weq, wek, wev, nq, nk, nv, att);
  k_node_ffn<<<NB * NN, 256, 0, stream>>>(x, att, nfc1_w, nfc1_b, ln1_g, ln1_b,
                                          nfc2_w, nfc2_b, nfc3_w, nfc3_b,
                                          ln2_g, ln2_b, outf);
  k_edge1<<<NB * NN, 512, 0, stream>>>(adj, outf, efc1_w, efc1_b, efc2_w, efc2_b,
                                       eln1_g, eln1_b, outadj);
  k_edge2<<<NB * NN, 512, 0, stream>>>(outadj, efc3_w, efc3_b, efc4_w, efc4_b,
                                       eln2_g, eln2_b);
}

// Round 7
// 563.796 us; speedup vs baseline: 1.2840x; 1.0115x over previous
//
#include <hip/hip_runtime.h>
#include <hip/hip_bf16.h>

typedef unsigned short u16;
typedef unsigned int u32;

#define NB 2
#define NN 384
#define ND 128
#define NE 64
#define NHD 8
#define NHID 256
#define EH1 384
#define EH2 128
#define LN_EPS 1e-5f
#define ATT_SCALE 0.17677669529663687f  // 1/sqrt(NODE_HIDDEN//HEADS)=1/sqrt(32)

#define XOUT_ELEMS (NB * NN * ND)                 // 98304
#define ADJ_ELEMS ((size_t)NB * NN * NN * NE)     // 18874368
#define OUT_ELEMS (XOUT_ELEMS + ADJ_ELEMS)        // 18972672 f32 elements
// f32 scratch carved from the TAIL of the adj-output region (dead until
// k_edge1 writes it, by which time scratch is fully consumed). No d_ws.
#define SCRATCH_F32 (4 * XOUT_ELEMS)              // nq,nk,nv,att

typedef __attribute__((ext_vector_type(4))) float f32x4;
typedef __attribute__((ext_vector_type(8))) short s16x8;
#define MFMA16(a, b, c) __builtin_amdgcn_mfma_f32_16x16x32_bf16(a, b, c, 0, 0, 0)

__device__ __forceinline__ float bflo(u32 u) {
  return __builtin_bit_cast(float, u << 16);
}
__device__ __forceinline__ float bfhi(u32 u) {
  return __builtin_bit_cast(float, u & 0xffff0000u);
}
__device__ __forceinline__ u16 bfr(float f) {
  return __builtin_bit_cast(u16, __float2bfloat16(f));
}
__device__ __forceinline__ float bfu(u16 h) {
  return __builtin_bit_cast(float, ((u32)h) << 16);
}
__device__ __forceinline__ u32 packbf(float a, float b) {
  return (u32)bfr(a) | ((u32)bfr(b) << 16);
}
__device__ __forceinline__ float wsum64(float v) {
#pragma unroll
  for (int o = 32; o > 0; o >>= 1) v += __shfl_xor(v, o, 64);
  return v;
}
__device__ __forceinline__ float wmax64(float v) {
#pragma unroll
  for (int o = 32; o > 0; o >>= 1) v = fmaxf(v, __shfl_xor(v, o, 64));
  return v;
}

// convert 8 consecutive f32 -> one bf16 weight fragment (short8)
__device__ __forceinline__ s16x8 cvt_frag(const float* p) {
  float4 a = *(const float4*)p;
  float4 c = *(const float4*)(p + 4);
  s16x8 r;
  r[0] = (short)bfr(a.x); r[1] = (short)bfr(a.y);
  r[2] = (short)bfr(a.z); r[3] = (short)bfr(a.w);
  r[4] = (short)bfr(c.x); r[5] = (short)bfr(c.y);
  r[6] = (short)bfr(c.z); r[7] = (short)bfr(c.w);
  return r;
}

// convert 8 f32 (two float4s) -> hi/lo bf16 pairs (16B each)
__device__ __forceinline__ void cvt8v(float4 a, float4 c, uint4& hi, uint4& lo) {
  float v[8] = {a.x, a.y, a.z, a.w, c.x, c.y, c.z, c.w};
  u32 hw[4], lw[4];
#pragma unroll
  for (int e = 0; e < 4; ++e) {
    u16 h0 = bfr(v[2 * e]), h1 = bfr(v[2 * e + 1]);
    u16 l0 = bfr(v[2 * e] - bfu(h0));
    u16 l1 = bfr(v[2 * e + 1] - bfu(h1));
    hw[e] = (u32)h0 | ((u32)h1 << 16);
    lw[e] = (u32)l0 | ((u32)l1 << 16);
  }
  hi.x = hw[0]; hi.y = hw[1]; hi.z = hw[2]; hi.w = hw[3];
  lo.x = lw[0]; lo.y = lw[1]; lo.z = lw[2]; lo.w = lw[3];
}

// convert 8 consecutive f32 -> hi/lo bf16 pairs (16B each)
__device__ __forceinline__ void cvt8_hl(const float* p, uint4& hi, uint4& lo) {
  cvt8v(*(const float4*)p, *(const float4*)(p + 4), hi, lo);
}

// ---------------- K1: nq/nk/nv = x @ w{q,k,v}.T (f32, plain) ----------------
__global__ void k_node_qkv(const float* __restrict__ x,
                           const float* __restrict__ wq,
                           const float* __restrict__ wk,
                           const float* __restrict__ wv,
                           float* __restrict__ nq, float* __restrict__ nk,
                           float* __restrict__ nv) {
  int row = blockIdx.x;  // b*N+i
  int t = threadIdx.x;   // 128
  __shared__ float xs[ND];
  xs[t] = x[row * ND + t];
  __syncthreads();
  float aq = 0.f, ak = 0.f, av = 0.f;
  for (int k = 0; k < ND; ++k) {
    float xv = xs[k];
    aq += xv * wq[t * ND + k];
    ak += xv * wk[t * ND + k];
    av += xv * wv[t * ND + k];
  }
  nq[row * ND + t] = aq;
  nk[row * ND + t] = ak;
  nv[row * ND + t] = av;
}

// ---------------- K2: attention, online-softmax fused single pass ----------
// Per block (b,i), wave = head h, 3 j-tiles of 128:
//  - T14 prefetch: tile t+1's adj loads issued during tile t's compute.
//  - scores via MFMA edge projections (hi/lo bf16 split) + shfl d-reduce;
//    nk values prefetched to registers before the MFMA loop.
//  - flash-style online (m, Z) per wave; psum[k=l] accumulated from the
//    STAGED LDS tile (hi+lo) -- no second adj pass.
//  - epilogue: p recomputed from raw scores; att = sum_j p nv_j + Ve psum.
#define ATJ 128
struct AttnS {
  u16 Ahi[ATJ][NE];     // 16KB, row stride 128B, byte ^= (row&7)<<4
  u16 Alo[ATJ][NE];     // 16KB
  float sc[NHD][NN];    // 12KB raw scores -> probs
  float pe[NHD][ATJ];   // 4KB per-tile e values
  float psum[NHD][NE];  // 2KB
  float part[4][ND];    // 2KB epilogue partials
};

__global__ void __launch_bounds__(512) k_attn(
    const float* __restrict__ adj,
    const float* __restrict__ weq,
    const float* __restrict__ wek,
    const float* __restrict__ wev,
    const float* __restrict__ nq,
    const float* __restrict__ nk,
    const float* __restrict__ nv,
    float* __restrict__ att) {
  __shared__ AttnS s;
  int bi = blockIdx.x;     // b*N + i
  int b = bi / NN;
  int t = threadIdx.x;     // 512
  int h = t >> 6;          // wave = head
  int l = t & 63;
  int lr = l & 15, lk = l >> 4;

  s16x8 BQ[2], BK[2];
  {
    const float* wqp = weq + (size_t)(h * 16 + lr) * NE + lk * 8;
    const float* wkp = wek + (size_t)(h * 16 + lr) * NE + lk * 8;
    BQ[0] = cvt_frag(wqp); BQ[1] = cvt_frag(wqp + 32);
    BK[0] = cvt_frag(wkp); BK[1] = cvt_frag(wkp + 32);
  }
  float nqd = nq[(size_t)bi * ND + h * 16 + lr];

  // staging assignment: thread handles units p=t and p=t+512 of 1024
  int row0 = t >> 3, u0 = t & 7;        // rows 0..63
  int row1 = row0 + 64, u1 = u0;        // rows 64..127
  float4 pa0, pb0, pa1, pb1;            // prefetch regs (tile 0)
  {
    const float* s0 = adj + ((size_t)bi * NN + row0) * NE + u0 * 8;
    const float* s1 = adj + ((size_t)bi * NN + row1) * NE + u1 * 8;
    pa0 = *(const float4*)s0; pb0 = *(const float4*)(s0 + 4);
    pa1 = *(const float4*)s1; pb1 = *(const float4*)(s1 + 4);
  }

  float m_run = -1e30f, lsum = 0.f, psacc = 0.f;

  for (int tile = 0; tile < NN / ATJ; ++tile) {
    int jbase = tile * ATJ;
    __syncthreads();  // previous tile's psum readers done
    {  // write prefetched tile to LDS (hi/lo, swizzled)
      uint4 hi, lo;
      cvt8v(pa0, pb0, hi, lo);
      int byt = (row0 * 128 + u0 * 16) ^ ((row0 & 7) << 4);
      *(uint4*)((char*)s.Ahi + byt) = hi;
      *(uint4*)((char*)s.Alo + byt) = lo;
      cvt8v(pa1, pb1, hi, lo);
      byt = (row1 * 128 + u1 * 16) ^ ((row1 & 7) << 4);
      *(uint4*)((char*)s.Ahi + byt) = hi;
      *(uint4*)((char*)s.Alo + byt) = lo;
    }
    __syncthreads();

    {  // T14: issue next tile's loads now; consumed after next barrier
      int tn = (tile < NN / ATJ - 1) ? tile + 1 : 0;
      const float* s0 = adj + ((size_t)bi * NN + tn * ATJ + row0) * NE + u0 * 8;
      const float* s1 = adj + ((size_t)bi * NN + tn * ATJ + row1) * NE + u1 * 8;
      pa0 = *(const float4*)s0; pb0 = *(const float4*)(s0 + 4);
      pa1 = *(const float4*)s1; pb1 = *(const float4*)(s1 + 4);
    }

    // prefetch this tile's nk values (batched, ILP-pipelined)
    float nkv[32];
    {
      const float* nkb =
          nk + ((size_t)b * NN + jbase + lk * 4) * ND + h * 16 + lr;
#pragma unroll
      for (int sub = 0; sub < 8; ++sub)
#pragma unroll
        for (int r = 0; r < 4; ++r)
          nkv[sub * 4 + r] = nkb[(size_t)(sub * 16 + r) * ND];
    }

    // scores for this tile
#pragma unroll
    for (int sub = 0; sub < ATJ / 16; ++sub) {
      int trow = sub * 16 + lr;
      int swz = (trow & 7) << 4;
      f32x4 eq = {0.f, 0.f, 0.f, 0.f}, ek = {0.f, 0.f, 0.f, 0.f};
#pragma unroll
      for (int ks = 0; ks < 2; ++ks) {
        int byt = (trow * 128 + ks * 64 + lk * 16) ^ swz;
        s16x8 ah = *(const s16x8*)((const char*)s.Ahi + byt);
        s16x8 al = *(const s16x8*)((const char*)s.Alo + byt);
        eq = MFMA16(ah, BQ[ks], eq);
        eq = MFMA16(al, BQ[ks], eq);
        ek = MFMA16(ah, BK[ks], ek);
        ek = MFMA16(al, BK[ks], ek);
      }
#pragma unroll
      for (int r = 0; r < 4; ++r) {
        int j = jbase + sub * 16 + lk * 4 + r;
        float kv = nkv[sub * 4 + r] + ek[r];
        float prod = (nqd + eq[r]) * kv;
#pragma unroll
        for (int o = 8; o > 0; o >>= 1) prod += __shfl_xor(prod, o, 64);
        if (lr == 0) s.sc[h][j] = prod * ATT_SCALE;
      }
    }
    __builtin_amdgcn_wave_barrier();  // order sc writes before same-wave reads

    // online (m, Z) update + psum accumulation from the staged tile
    {
      float s0v = s.sc[h][jbase + l];
      float s1v = s.sc[h][jbase + 64 + l];
      float tmax = wmax64(fmaxf(s0v, s1v));
      float m_new = fmaxf(m_run, tmax);
      float f = __expf(m_run - m_new);  // 0 on first tile
      float e0 = __expf(s0v - m_new), e1 = __expf(s1v - m_new);
      s.pe[h][l] = e0;
      s.pe[h][l + 64] = e1;
      lsum = lsum * f + wsum64(e0 + e1);
      psacc *= f;
      m_run = m_new;
      __builtin_amdgcn_wave_barrier();  // pe writes before same-wave reads
#pragma unroll 8
      for (int j = 0; j < ATJ; ++j) {
        float pj = s.pe[h][j];
        int byt = (j * 128 + l * 2) ^ ((j & 7) << 4);
        float av = bfu(*(const u16*)((const char*)s.Ahi + byt)) +
                   bfu(*(const u16*)((const char*)s.Alo + byt));
        psacc += pj * av;
      }
    }
  }

  // finalize: normalize scores -> p, psum -> psum/Z
  {
    float rinv = 1.f / lsum;
#pragma unroll
    for (int r = 0; r < NN / 64; ++r) {
      float sv = s.sc[h][l + 64 * r];
      s.sc[h][l + 64 * r] = __expf(sv - m_run) * rinv;
    }
    s.psum[h][l] = psacc * rinv;
  }
  __syncthreads();

  // ---------------- epilogue: att = sum_j p nv_j + Ve psum ----------------
  {
    int c = t & 127, grp = t >> 7;  // 4-way j-split
    int hc = c >> 4;
    float acc = 0.f;
    const float* nvb = nv + (size_t)b * NN * ND + c;
    const float* pr = s.sc[hc];
#pragma unroll 4
    for (int j = grp * (NN / 4); j < (grp + 1) * (NN / 4); ++j)
      acc += pr[j] * nvb[(size_t)j * ND];
    s.part[grp][c] = acc;
  }
  __syncthreads();
  if (t < ND) {
    int c = t, hc = c >> 4;
    float acc = s.part[0][c] + s.part[1][c] + s.part[2][c] + s.part[3][c];
    const float4* wr = (const float4*)(wev + c * NE);
    const float* ps = s.psum[hc];
#pragma unroll
    for (int k4 = 0; k4 < NE / 4; ++k4) {
      float4 w4 = wr[k4];
      acc += w4.x * ps[4 * k4] + w4.y * ps[4 * k4 + 1] +
             w4.z * ps[4 * k4 + 2] + w4.w * ps[4 * k4 + 3];
    }
    // channel c -> (h=c/16, d=c%16); output position d*HEADS + h
    att[(size_t)bi * ND + (c & 15) * NHD + hc] = acc;
  }
}

// ---------------- K3: nfc1 + LN1 + FFN + LN2, wave-parallel LNs ------------
struct FfnS {
  float atts[ND];
  float tvb[ND];
  float x1[ND];
  float hb[NHID];
  float stats[2];  // mean, rstd
};

__global__ void k_node_ffn(const float* __restrict__ x,
                           const float* __restrict__ att,
                           const float* __restrict__ w1, const float* __restrict__ b1,
                           const float* __restrict__ g1, const float* __restrict__ bb1,
                           const float* __restrict__ w2, const float* __restrict__ b2,
                           const float* __restrict__ w3, const float* __restrict__ b3,
                           const float* __restrict__ g2, const float* __restrict__ bb2,
                           float* __restrict__ xout) {
  __shared__ FfnS s;
  int row = blockIdx.x;
  int tid = threadIdx.x;  // 256
  if (tid < ND) s.atts[tid] = att[row * ND + tid];
  __syncthreads();

  if (tid < ND) {
    float acc = b1[tid];
    for (int k = 0; k < ND; ++k) acc += s.atts[k] * w1[tid * ND + k];
    s.tvb[tid] = x[row * ND + tid] + acc;
  }
  __syncthreads();
  if (tid < 64) {  // wave 0: LN1 stats over 128 via shuffle reduce
    float v0 = s.tvb[tid], v1 = s.tvb[tid + 64];
    float m = wsum64(v0 + v1) * (1.f / ND);
    float d0 = v0 - m, d1 = v1 - m;
    float var = wsum64(d0 * d0 + d1 * d1) * (1.f / ND);
    if (tid == 0) {
      s.stats[0] = m;
      s.stats[1] = rsqrtf(var + LN_EPS);
    }
  }
  __syncthreads();
  if (tid < ND)
    s.x1[tid] = (s.tvb[tid] - s.stats[0]) * s.stats[1] * g1[tid] + bb1[tid];
  __syncthreads();

  {
    float acc = b2[tid];
    for (int k = 0; k < ND; ++k) acc += s.x1[k] * w2[tid * ND + k];
    s.hb[tid] = fmaxf(acc, 0.f);
  }
  __syncthreads();

  if (tid < ND) {
    float acc = b3[tid];
    for (int k = 0; k < NHID; ++k) acc += s.hb[k] * w3[tid * NHID + k];
    s.tvb[tid] = s.x1[tid] + acc;
  }
  __syncthreads();
  if (tid < 64) {  // wave 0: LN2 stats
    float v0 = s.tvb[tid], v1 = s.tvb[tid + 64];
    float m = wsum64(v0 + v1) * (1.f / ND);
    float d0 = v0 - m, d1 = v1 - m;
    float var = wsum64(d0 * d0 + d1 * d1) * (1.f / ND);
    if (tid == 0) {
      s.stats[0] = m;
      s.stats[1] = rsqrtf(var + LN_EPS);
    }
  }
  __syncthreads();
  if (tid < ND) {
    float o = (s.tvb[tid] - s.stats[0]) * s.stats[1] * g2[tid] + bb2[tid];
    xout[row * ND + tid] = o;  // FLOAT32 output
  }
}

// ---------------- K4: edge stage 1 via MFMA, factored node projections -----
// Per block (b,i), 12 M-tiles of 32 j-rows:
//   L1: [32x256](a_ij|a_ji|x_j) @ W1abc^T (MFMA, hi/lo split)
//       + (x_i @ W1d^T + b1) [per-thread f32xbf16] -> relu -> H1
//   L2: H1 @ W2^T + a_ij ; residual + LN over 64 cols.
#define EMT 32

struct E1M {
  u16 Ahi[EMT][256];   // 16KB swizzled, row stride 512B
  u16 Alo[EMT][256];   // 16KB
  u16 Hhi[EMT][NE];    // 4KB swizzled, row stride 128B
  u16 Hlo[EMT][NE];    // 4KB ; Hhi+Hlo reused as f32 tvb[32][64] for LN
};

__global__ void __launch_bounds__(512) k_edge1(
    const float* __restrict__ adj, const float* __restrict__ xq,
    const float* __restrict__ w1, const float* __restrict__ b1,
    const float* __restrict__ w2, const float* __restrict__ b2,
    const float* __restrict__ g, const float* __restrict__ bb,
    float* __restrict__ adj1out) {
  __shared__ E1M s;
  int bi = blockIdx.x;
  int b = bi / NN, i = bi % NN;
  int t = threadIdx.x;      // 512
  int w = t >> 6, l = t & 63;
  int m16 = (w & 1) * 16;   // wave's M sub-tile base
  int n16 = (w >> 1) * 16;  // wave's N sub-tile base
  int lr = l & 15, lk = l >> 4;

  // per-wave weight fragments (f32 -> bf16 once per block), cols 0..255
  s16x8 B1[8], B2[2];
  {
    const float* wr = w1 + (size_t)(n16 + lr) * EH1 + lk * 8;
#pragma unroll
    for (int ks = 0; ks < 8; ++ks) B1[ks] = cvt_frag(wr + ks * 32);
    const float* w2r = w2 + (size_t)(n16 + lr) * NE + lk * 8;
#pragma unroll
    for (int ks = 0; ks < 2; ++ks) B2[ks] = cvt_frag(w2r + ks * 32);
  }
  // x_i @ W1d^T (cols 256..383), f32 activation x bf16 weight (exact-act).
  float bias1;
  {
    float ci = 0.f;
    const float* xr = xq + (size_t)bi * ND;
    const float* wr = w1 + (size_t)(n16 + lr) * EH1 + 256;
#pragma unroll 4
    for (int k = 0; k < ND; ++k) ci += xr[k] * bfu(bfr(wr[k]));
    bias1 = b1[n16 + lr] + ci;
  }
  float bias2 = b2[n16 + lr];
  float gl = g[l], bl = bb[l];

  for (int mt = 0; mt < NN / EMT; ++mt) {
    int jbase = mt * EMT;
    __syncthreads();
    // stage tile: 32 rows x 32 x 16B units (a_ij 8 | a_ji 8 | x_j 16), hi/lo
    for (int p = t; p < EMT * 32; p += 512) {
      int row = p >> 5, uu = p & 31;
      const float* src;
      if (uu < 8)
        src = adj + ((size_t)bi * NN + jbase + row) * NE + uu * 8;
      else if (uu < 16)
        src = adj + ((size_t)(b * NN + jbase + row) * NN + i) * NE + (uu - 8) * 8;
      else
        src = xq + (size_t)(b * NN + jbase + row) * ND + (uu - 16) * 8;
      uint4 hi, lo;
      cvt8_hl(src, hi, lo);
      int byt = (row * 512 + uu * 16) ^ ((row & 7) << 4);
      *(uint4*)((char*)s.Ahi + byt) = hi;
      *(uint4*)((char*)s.Alo + byt) = lo;
    }
    __syncthreads();

    // layer1: K=256
    f32x4 acc = {0.f, 0.f, 0.f, 0.f};
    int arow = m16 + lr;
    int aswz = (arow & 7) << 4;
#pragma unroll
    for (int ks = 0; ks < 8; ++ks) {
      int byt = (arow * 512 + ks * 64 + lk * 16) ^ aswz;
      s16x8 ah = *(const s16x8*)((const char*)s.Ahi + byt);
      s16x8 al = *(const s16x8*)((const char*)s.Alo + byt);
      acc = MFMA16(ah, B1[ks], acc);
      acc = MFMA16(al, B1[ks], acc);
    }
#pragma unroll
    for (int r = 0; r < 4; ++r) {
      float hv = fmaxf(acc[r] + bias1, 0.f);
      u16 hh = bfr(hv);
      u16 hl = bfr(hv - bfu(hh));
      int row = m16 + lk * 4 + r;
      int byt = (row * 128 + (n16 + lr) * 2) ^ ((row & 7) << 4);
      *(u16*)((char*)s.Hhi + byt) = hh;
      *(u16*)((char*)s.Hlo + byt) = hl;
    }
    __syncthreads();

    // layer2
    f32x4 acc2 = {0.f, 0.f, 0.f, 0.f};
#pragma unroll
    for (int ks = 0; ks < 2; ++ks) {
      int byt = (arow * 128 + ks * 64 + lk * 16) ^ aswz;
      s16x8 ah = *(const s16x8*)((const char*)s.Hhi + byt);
      s16x8 al = *(const s16x8*)((const char*)s.Hlo + byt);
      acc2 = MFMA16(ah, B2[ks], acc2);
      acc2 = MFMA16(al, B2[ks], acc2);
    }
    __syncthreads();  // H reads done -> reuse as f32 tv buffer
    float* tvb = (float*)s.Hhi;
#pragma unroll
    for (int r = 0; r < 4; ++r) {
      int row = m16 + lk * 4 + r;
      int col = n16 + lr;
      int abyt = (row * 512 + col * 2) ^ ((row & 7) << 4);
      float aorig = bfu(*(const u16*)((const char*)s.Ahi + abyt)) +
                    bfu(*(const u16*)((const char*)s.Alo + abyt));
      tvb[row * NE + col] = aorig + acc2[r] + bias2;
    }
    __syncthreads();
    // LN: wave w handles rows w*4..w*4+3, lane = col
#pragma unroll
    for (int rr = 0; rr < EMT / 8; ++rr) {
      int row = w * (EMT / 8) + rr;
      float tv = tvb[row * NE + l];
      float mean = wsum64(tv) * (1.f / NE);
      float dv = tv - mean;
      float var = wsum64(dv * dv) * (1.f / NE);
      float o = dv * rsqrtf(var + LN_EPS) * gl + bl;
      adj1out[((size_t)bi * NN + jbase + row) * NE + l] = o;
    }
  }
}

// ---------------- K5: edge stage 2 via MFMA (in-place on d_out adj) --------
struct E2M {
  u16 Ahi[EMT][NE];    // 4KB swizzled, row stride 128B
  u16 Alo[EMT][NE];    // 4KB
  u16 Hhi[EMT][EH2];   // 8KB swizzled, row stride 256B ; reused as f32 tvb
  u16 Hlo[EMT][EH2];   // 8KB
};

__global__ void __launch_bounds__(512) k_edge2(
    float* __restrict__ adjio,
    const float* __restrict__ w3, const float* __restrict__ b3,
    const float* __restrict__ w4, const float* __restrict__ b4,
    const float* __restrict__ g, const float* __restrict__ bb) {
  __shared__ E2M s;
  int bi = blockIdx.x;
  int t = threadIdx.x;      // 512
  int w = t >> 6, l = t & 63;
  int m16 = (w & 1) * 16;
  int nb = (w >> 1) * 2;    // layer3 n16 pair base (0,2,4,6)
  int n16 = (w >> 1) * 16;  // layer4 col base
  int lr = l & 15, lk = l >> 4;

  s16x8 B3[2][2], B4[4];
  {
#pragma unroll
    for (int n = 0; n < 2; ++n) {
      const float* wr = w3 + (size_t)((nb + n) * 16 + lr) * NE + lk * 8;
#pragma unroll
      for (int ks = 0; ks < 2; ++ks) B3[n][ks] = cvt_frag(wr + ks * 32);
    }
    const float* w4r = w4 + (size_t)(n16 + lr) * EH2 + lk * 8;
#pragma unroll
    for (int ks = 0; ks < 4; ++ks) B4[ks] = cvt_frag(w4r + ks * 32);
  }
  float bias3[2] = {b3[nb * 16 + lr], b3[(nb + 1) * 16 + lr]};
  float bias4 = b4[n16 + lr];
  float gl = g[l], bl = bb[l];

  for (int mt = 0; mt < NN / EMT; ++mt) {
    int jbase = mt * EMT;
    __syncthreads();
    for (int p = t; p < EMT * 8; p += 512) {  // 256 units, threads<256 active
      int row = p >> 3, u = p & 7;
      const float* src = adjio + ((size_t)bi * NN + jbase + row) * NE + u * 8;
      uint4 hi, lo;
      cvt8_hl(src, hi, lo);
      int byt = (row * 128 + u * 16) ^ ((row & 7) << 4);
      *(uint4*)((char*)s.Ahi + byt) = hi;
      *(uint4*)((char*)s.Alo + byt) = lo;
    }
    __syncthreads();

    // layer3: out [32 x 128]
    f32x4 a3[2] = {{0.f, 0.f, 0.f, 0.f}, {0.f, 0.f, 0.f, 0.f}};
    int arow = m16 + lr;
    int aswz = (arow & 7) << 4;
#pragma unroll
    for (int ks = 0; ks < 2; ++ks) {
      int byt = (arow * 128 + ks * 64 + lk * 16) ^ aswz;
      s16x8 ah = *(const s16x8*)((const char*)s.Ahi + byt);
      s16x8 al = *(const s16x8*)((const char*)s.Alo + byt);
#pragma unroll
      for (int n = 0; n < 2; ++n) {
        a3[n] = MFMA16(ah, B3[n][ks], a3[n]);
        a3[n] = MFMA16(al, B3[n][ks], a3[n]);
      }
    }
#pragma unroll
    for (int n = 0; n < 2; ++n) {
#pragma unroll
      for (int r = 0; r < 4; ++r) {
        float hv = fmaxf(a3[n][r] + bias3[n], 0.f);
        u16 hh = bfr(hv);
        u16 hl = bfr(hv - bfu(hh));
        int row = m16 + lk * 4 + r;
        int byt = (row * 256 + ((nb + n) * 16 + lr) * 2) ^ ((row & 7) << 4);
        *(u16*)((char*)s.Hhi + byt) = hh;
        *(u16*)((char*)s.Hlo + byt) = hl;
      }
    }
    __syncthreads();

    // layer4: out [32 x 64]
    f32x4 a4 = {0.f, 0.f, 0.f, 0.f};
#pragma unroll
    for (int ks = 0; ks < 4; ++ks) {
      int byt = (arow * 256 + ks * 64 + lk * 16) ^ aswz;
      s16x8 ah = *(const s16x8*)((const char*)s.Hhi + byt);
      s16x8 al = *(const s16x8*)((const char*)s.Hlo + byt);
      a4 = MFMA16(ah, B4[ks], a4);
      a4 = MFMA16(al, B4[ks], a4);
    }
    __syncthreads();  // H reads done -> reuse as f32 tv buffer
    float* tvb = (float*)s.Hhi;
#pragma unroll
    for (int r = 0; r < 4; ++r) {
      int row = m16 + lk * 4 + r;
      int col = n16 + lr;
      int abyt = (row * 128 + col * 2) ^ ((row & 7) << 4);
      float aorig = bfu(*(const u16*)((const char*)s.Ahi + abyt)) +
                    bfu(*(const u16*)((const char*)s.Alo + abyt));
      tvb[row * NE + col] = aorig + a4[r] + bias4;
    }
    __syncthreads();
#pragma unroll
    for (int rr = 0; rr < EMT / 8; ++rr) {
      int row = w * (EMT / 8) + rr;
      float tv = tvb[row * NE + l];
      float mean = wsum64(tv) * (1.f / NE);
      float dv = tv - mean;
      float var = wsum64(dv * dv) * (1.f / NE);
      float o = dv * rsqrtf(var + LN_EPS) * gl + bl;
      adjio[((size_t)bi * NN + jbase + row) * NE + l] = o;
    }
  }
}

extern "C" void kernel_launch(void* const* d_in, const int* in_sizes, int n_in,
                              void* d_out, int out_size, void* d_ws, size_t ws_size,
                              hipStream_t stream) {
  (void)in_sizes; (void)n_in; (void)out_size; (void)d_ws; (void)ws_size;
  const float* x      = (const float*)d_in[0];
  const float* adj    = (const float*)d_in[1];
  const float* wnq    = (const float*)d_in[2];
  const float* wnk    = (const float*)d_in[3];
  const float* wnv    = (const float*)d_in[4];
  const float* weq    = (const float*)d_in[5];
  const float* wek    = (const float*)d_in[6];
  const float* wev    = (const float*)d_in[7];
  const float* nfc1_w = (const float*)d_in[8];
  const float* nfc1_b = (const float*)d_in[9];
  const float* ln1_g  = (const float*)d_in[10];
  const float* ln1_b  = (const float*)d_in[11];
  const float* nfc2_w = (const float*)d_in[12];
  const float* nfc2_b = (const float*)d_in[13];
  const float* nfc3_w = (const float*)d_in[14];
  const float* nfc3_b = (const float*)d_in[15];
  const float* ln2_g  = (const float*)d_in[16];
  const float* ln2_b  = (const float*)d_in[17];
  const float* efc1_w = (const float*)d_in[18];
  const float* efc1_b = (const float*)d_in[19];
  const float* efc2_w = (const float*)d_in[20];
  const float* efc2_b = (const float*)d_in[21];
  const float* eln1_g = (const float*)d_in[22];
  const float* eln1_b = (const float*)d_in[23];
  const float* efc3_w = (const float*)d_in[24];
  const float* efc3_b = (const float*)d_in[25];
  const float* efc4_w = (const float*)d_in[26];
  const float* efc4_b = (const float*)d_in[27];
  const float* eln2_g = (const float*)d_in[28];
  const float* eln2_b = (const float*)d_in[29];

  float* outf = (float*)d_out;          // FLOAT32 output buffer: [x ; adj]
  float* outadj = outf + XOUT_ELEMS;

  // f32 scratch in the tail of the adj-output region (dead until k_edge1).
  float* scratch = outf + OUT_ELEMS - SCRATCH_F32;
  float* nq  = scratch;
  float* nk  = scratch + XOUT_ELEMS;
  float* nv  = scratch + 2 * XOUT_ELEMS;
  float* att = scratch + 3 * XOUT_ELEMS;

  k_node_qkv<<<NB * NN, 128, 0, stream>>>(x, wnq, wnk, wnv, nq, nk, nv);
  k_attn<<<NB * NN, 512, 0, stream>>>(adj, weq, wek, wev, nq, nk, nv, att);
  k_node_ffn<<<NB * NN, 256, 0, stream>>>(x, att, nfc1_w, nfc1_b, ln1_g, ln1_b,
                                          nfc2_w, nfc2_b, nfc3_w, nfc3_b,
                                          ln2_g, ln2_b, outf);
  k_edge1<<<NB * NN, 512, 0, stream>>>(adj, outf, efc1_w, efc1_b, efc2_w, efc2_b,
                                       eln1_g, eln1_b, outadj);
  k_edge2<<<NB * NN, 512, 0, stream>>>(outadj, efc3_w, efc3_b, efc4_w, efc4_b,
                                       eln2_g, eln2_b);
}

// Round 8
// 523.208 us; speedup vs baseline: 1.3836x; 1.0776x over previous
//
#include <hip/hip_runtime.h>
#include <hip/hip_bf16.h>

typedef unsigned short u16;
typedef unsigned int u32;

#define NB 2
#define NN 384
#define ND 128
#define NE 64
#define NHD 8
#define NHID 256
#define EH1 384
#define EH2 128
#define LN_EPS 1e-5f
#define ATT_SCALE 0.17677669529663687f  // 1/sqrt(NODE_HIDDEN//HEADS)=1/sqrt(32)

#define XOUT_ELEMS (NB * NN * ND)                 // 98304
#define ADJ_ELEMS ((size_t)NB * NN * NN * NE)     // 18874368
#define OUT_ELEMS (XOUT_ELEMS + ADJ_ELEMS)        // 18972672 f32 elements
// f32 scratch carved from the TAIL of the adj-output region (dead until
// k_edge1 writes it, by which time scratch is fully consumed). No d_ws.
#define SCRATCH_F32 (4 * XOUT_ELEMS)              // nq,nk,nv,att

typedef __attribute__((ext_vector_type(4))) float f32x4;
typedef __attribute__((ext_vector_type(8))) short s16x8;
#define MFMA16(a, b, c) __builtin_amdgcn_mfma_f32_16x16x32_bf16(a, b, c, 0, 0, 0)

__device__ __forceinline__ float bflo(u32 u) {
  return __builtin_bit_cast(float, u << 16);
}
__device__ __forceinline__ float bfhi(u32 u) {
  return __builtin_bit_cast(float, u & 0xffff0000u);
}
__device__ __forceinline__ u16 bfr(float f) {
  return __builtin_bit_cast(u16, __float2bfloat16(f));
}
__device__ __forceinline__ float bfu(u16 h) {
  return __builtin_bit_cast(float, ((u32)h) << 16);
}
__device__ __forceinline__ u32 packbf(float a, float b) {
  return (u32)bfr(a) | ((u32)bfr(b) << 16);
}
__device__ __forceinline__ float wsum64(float v) {
#pragma unroll
  for (int o = 32; o > 0; o >>= 1) v += __shfl_xor(v, o, 64);
  return v;
}
__device__ __forceinline__ float wmax64(float v) {
#pragma unroll
  for (int o = 32; o > 0; o >>= 1) v = fmaxf(v, __shfl_xor(v, o, 64));
  return v;
}

// convert 8 consecutive f32 -> one bf16 weight fragment (short8)
__device__ __forceinline__ s16x8 cvt_frag(const float* p) {
  float4 a = *(const float4*)p;
  float4 c = *(const float4*)(p + 4);
  s16x8 r;
  r[0] = (short)bfr(a.x); r[1] = (short)bfr(a.y);
  r[2] = (short)bfr(a.z); r[3] = (short)bfr(a.w);
  r[4] = (short)bfr(c.x); r[5] = (short)bfr(c.y);
  r[6] = (short)bfr(c.z); r[7] = (short)bfr(c.w);
  return r;
}

// convert 8 f32 (two float4s) -> hi/lo bf16 pairs (16B each)
__device__ __forceinline__ void cvt8v(float4 a, float4 c, uint4& hi, uint4& lo) {
  float v[8] = {a.x, a.y, a.z, a.w, c.x, c.y, c.z, c.w};
  u32 hw[4], lw[4];
#pragma unroll
  for (int e = 0; e < 4; ++e) {
    u16 h0 = bfr(v[2 * e]), h1 = bfr(v[2 * e + 1]);
    u16 l0 = bfr(v[2 * e] - bfu(h0));
    u16 l1 = bfr(v[2 * e + 1] - bfu(h1));
    hw[e] = (u32)h0 | ((u32)h1 << 16);
    lw[e] = (u32)l0 | ((u32)l1 << 16);
  }
  hi.x = hw[0]; hi.y = hw[1]; hi.z = hw[2]; hi.w = hw[3];
  lo.x = lw[0]; lo.y = lw[1]; lo.z = lw[2]; lo.w = lw[3];
}

// convert 8 consecutive f32 -> hi/lo bf16 pairs (16B each)
__device__ __forceinline__ void cvt8_hl(const float* p, uint4& hi, uint4& lo) {
  cvt8v(*(const float4*)p, *(const float4*)(p + 4), hi, lo);
}

// ---------------- K1: nq/nk/nv = x @ w{q,k,v}.T (f32, plain) ----------------
__global__ void k_node_qkv(const float* __restrict__ x,
                           const float* __restrict__ wq,
                           const float* __restrict__ wk,
                           const float* __restrict__ wv,
                           float* __restrict__ nq, float* __restrict__ nk,
                           float* __restrict__ nv) {
  int row = blockIdx.x;  // b*N+i
  int t = threadIdx.x;   // 128
  __shared__ float xs[ND];
  xs[t] = x[row * ND + t];
  __syncthreads();
  float aq = 0.f, ak = 0.f, av = 0.f;
  for (int k = 0; k < ND; ++k) {
    float xv = xs[k];
    aq += xv * wq[t * ND + k];
    ak += xv * wk[t * ND + k];
    av += xv * wv[t * ND + k];
  }
  nq[row * ND + t] = aq;
  nk[row * ND + t] = ak;
  nv[row * ND + t] = av;
}

// ---------------- K2: attention, online-softmax fused, ATJ=64 --------------
// Per block (b,i), wave = head h, 6 j-tiles of 64 (34KB LDS -> 4 blocks/CU):
//  - T14 prefetch: tile t+1's adj loads issued during tile t's compute.
//  - scores via MFMA edge projections (hi/lo bf16 split) + shfl d-reduce;
//    nk values prefetched to registers before the MFMA loop.
//  - flash-style online (m, Z) per wave; psum[k=l] accumulated from the
//    staged LDS tile, HI-ONLY (error ~4e-4 into att, below the bf16-weight
//    error floor) -- no second adj pass.
//  - epilogue: p recomputed from raw scores; att = sum_j p nv_j + Ve psum.
#define ATJ 64
struct AttnS {
  u16 Ahi[ATJ][NE];     // 8KB, row stride 128B, byte ^= (row&7)<<4
  u16 Alo[ATJ][NE];     // 8KB
  float sc[NHD][NN];    // 12KB raw scores -> probs
  float pe[NHD][ATJ];   // 2KB per-tile e values
  float psum[NHD][NE];  // 2KB
  float part[4][ND];    // 2KB epilogue partials
};                      // 34KB

__global__ void __launch_bounds__(512) k_attn(
    const float* __restrict__ adj,
    const float* __restrict__ weq,
    const float* __restrict__ wek,
    const float* __restrict__ wev,
    const float* __restrict__ nq,
    const float* __restrict__ nk,
    const float* __restrict__ nv,
    float* __restrict__ att) {
  __shared__ AttnS s;
  int bi = blockIdx.x;     // b*N + i
  int b = bi / NN;
  int t = threadIdx.x;     // 512
  int h = t >> 6;          // wave = head
  int l = t & 63;
  int lr = l & 15, lk = l >> 4;

  s16x8 BQ[2], BK[2];
  {
    const float* wqp = weq + (size_t)(h * 16 + lr) * NE + lk * 8;
    const float* wkp = wek + (size_t)(h * 16 + lr) * NE + lk * 8;
    BQ[0] = cvt_frag(wqp); BQ[1] = cvt_frag(wqp + 32);
    BK[0] = cvt_frag(wkp); BK[1] = cvt_frag(wkp + 32);
  }
  float nqd = nq[(size_t)bi * ND + h * 16 + lr];

  // staging: thread handles exactly 1 of 512 16B-units per tile
  int row0 = t >> 3, u0 = t & 7;        // rows 0..63
  float4 pa0, pb0;                      // prefetch regs (tile 0)
  {
    const float* s0 = adj + ((size_t)bi * NN + row0) * NE + u0 * 8;
    pa0 = *(const float4*)s0; pb0 = *(const float4*)(s0 + 4);
  }

  float m_run = -1e30f, lsum = 0.f, psacc = 0.f;

  for (int tile = 0; tile < NN / ATJ; ++tile) {
    int jbase = tile * ATJ;
    __syncthreads();  // previous tile's psum readers done
    {  // write prefetched tile to LDS (hi/lo, swizzled)
      uint4 hi, lo;
      cvt8v(pa0, pb0, hi, lo);
      int byt = (row0 * 128 + u0 * 16) ^ ((row0 & 7) << 4);
      *(uint4*)((char*)s.Ahi + byt) = hi;
      *(uint4*)((char*)s.Alo + byt) = lo;
    }
    __syncthreads();

    {  // T14: issue next tile's loads now; consumed after next barrier
      int tn = (tile < NN / ATJ - 1) ? tile + 1 : 0;
      const float* s0 = adj + ((size_t)bi * NN + tn * ATJ + row0) * NE + u0 * 8;
      pa0 = *(const float4*)s0; pb0 = *(const float4*)(s0 + 4);
    }

    // prefetch this tile's nk values (batched, ILP-pipelined)
    float nkv[16];
    {
      const float* nkb =
          nk + ((size_t)b * NN + jbase + lk * 4) * ND + h * 16 + lr;
#pragma unroll
      for (int sub = 0; sub < 4; ++sub)
#pragma unroll
        for (int r = 0; r < 4; ++r)
          nkv[sub * 4 + r] = nkb[(size_t)(sub * 16 + r) * ND];
    }

    // scores for this tile
#pragma unroll
    for (int sub = 0; sub < ATJ / 16; ++sub) {
      int trow = sub * 16 + lr;
      int swz = (trow & 7) << 4;
      f32x4 eq = {0.f, 0.f, 0.f, 0.f}, ek = {0.f, 0.f, 0.f, 0.f};
#pragma unroll
      for (int ks = 0; ks < 2; ++ks) {
        int byt = (trow * 128 + ks * 64 + lk * 16) ^ swz;
        s16x8 ah = *(const s16x8*)((const char*)s.Ahi + byt);
        s16x8 al = *(const s16x8*)((const char*)s.Alo + byt);
        eq = MFMA16(ah, BQ[ks], eq);
        eq = MFMA16(al, BQ[ks], eq);
        ek = MFMA16(ah, BK[ks], ek);
        ek = MFMA16(al, BK[ks], ek);
      }
#pragma unroll
      for (int r = 0; r < 4; ++r) {
        int j = jbase + sub * 16 + lk * 4 + r;
        float kv = nkv[sub * 4 + r] + ek[r];
        float prod = (nqd + eq[r]) * kv;
#pragma unroll
        for (int o = 8; o > 0; o >>= 1) prod += __shfl_xor(prod, o, 64);
        if (lr == 0) s.sc[h][j] = prod * ATT_SCALE;
      }
    }
    __builtin_amdgcn_wave_barrier();  // order sc writes before same-wave reads

    // online (m, Z) update + psum accumulation from the staged tile (hi-only)
    {
      float s0v = s.sc[h][jbase + l];
      float tmax = wmax64(s0v);
      float m_new = fmaxf(m_run, tmax);
      float f = __expf(m_run - m_new);  // 0 on first tile
      float e0 = __expf(s0v - m_new);
      s.pe[h][l] = e0;
      lsum = lsum * f + wsum64(e0);
      psacc *= f;
      m_run = m_new;
      __builtin_amdgcn_wave_barrier();  // pe writes before same-wave reads
#pragma unroll 8
      for (int j = 0; j < ATJ; ++j) {
        float pj = s.pe[h][j];
        int byt = (j * 128 + l * 2) ^ ((j & 7) << 4);
        float av = bfu(*(const u16*)((const char*)s.Ahi + byt));
        psacc += pj * av;
      }
    }
  }

  // finalize: normalize scores -> p, psum -> psum/Z
  {
    float rinv = 1.f / lsum;
#pragma unroll
    for (int r = 0; r < NN / 64; ++r) {
      float sv = s.sc[h][l + 64 * r];
      s.sc[h][l + 64 * r] = __expf(sv - m_run) * rinv;
    }
    s.psum[h][l] = psacc * rinv;
  }
  __syncthreads();

  // ---------------- epilogue: att = sum_j p nv_j + Ve psum ----------------
  {
    int c = t & 127, grp = t >> 7;  // 4-way j-split
    int hc = c >> 4;
    float acc = 0.f;
    const float* nvb = nv + (size_t)b * NN * ND + c;
    const float* pr = s.sc[hc];
#pragma unroll 4
    for (int j = grp * (NN / 4); j < (grp + 1) * (NN / 4); ++j)
      acc += pr[j] * nvb[(size_t)j * ND];
    s.part[grp][c] = acc;
  }
  __syncthreads();
  if (t < ND) {
    int c = t, hc = c >> 4;
    float acc = s.part[0][c] + s.part[1][c] + s.part[2][c] + s.part[3][c];
    const float4* wr = (const float4*)(wev + c * NE);
    const float* ps = s.psum[hc];
#pragma unroll
    for (int k4 = 0; k4 < NE / 4; ++k4) {
      float4 w4 = wr[k4];
      acc += w4.x * ps[4 * k4] + w4.y * ps[4 * k4 + 1] +
             w4.z * ps[4 * k4 + 2] + w4.w * ps[4 * k4 + 3];
    }
    // channel c -> (h=c/16, d=c%16); output position d*HEADS + h
    att[(size_t)bi * ND + (c & 15) * NHD + hc] = acc;
  }
}

// ---------------- K3: nfc1 + LN1 + FFN + LN2, wave-parallel LNs ------------
struct FfnS {
  float atts[ND];
  float tvb[ND];
  float x1[ND];
  float hb[NHID];
  float stats[2];  // mean, rstd
};

__global__ void k_node_ffn(const float* __restrict__ x,
                           const float* __restrict__ att,
                           const float* __restrict__ w1, const float* __restrict__ b1,
                           const float* __restrict__ g1, const float* __restrict__ bb1,
                           const float* __restrict__ w2, const float* __restrict__ b2,
                           const float* __restrict__ w3, const float* __restrict__ b3,
                           const float* __restrict__ g2, const float* __restrict__ bb2,
                           float* __restrict__ xout) {
  __shared__ FfnS s;
  int row = blockIdx.x;
  int tid = threadIdx.x;  // 256
  if (tid < ND) s.atts[tid] = att[row * ND + tid];
  __syncthreads();

  if (tid < ND) {
    float acc = b1[tid];
    for (int k = 0; k < ND; ++k) acc += s.atts[k] * w1[tid * ND + k];
    s.tvb[tid] = x[row * ND + tid] + acc;
  }
  __syncthreads();
  if (tid < 64) {  // wave 0: LN1 stats over 128 via shuffle reduce
    float v0 = s.tvb[tid], v1 = s.tvb[tid + 64];
    float m = wsum64(v0 + v1) * (1.f / ND);
    float d0 = v0 - m, d1 = v1 - m;
    float var = wsum64(d0 * d0 + d1 * d1) * (1.f / ND);
    if (tid == 0) {
      s.stats[0] = m;
      s.stats[1] = rsqrtf(var + LN_EPS);
    }
  }
  __syncthreads();
  if (tid < ND)
    s.x1[tid] = (s.tvb[tid] - s.stats[0]) * s.stats[1] * g1[tid] + bb1[tid];
  __syncthreads();

  {
    float acc = b2[tid];
    for (int k = 0; k < ND; ++k) acc += s.x1[k] * w2[tid * ND + k];
    s.hb[tid] = fmaxf(acc, 0.f);
  }
  __syncthreads();

  if (tid < ND) {
    float acc = b3[tid];
    for (int k = 0; k < NHID; ++k) acc += s.hb[k] * w3[tid * NHID + k];
    s.tvb[tid] = s.x1[tid] + acc;
  }
  __syncthreads();
  if (tid < 64) {  // wave 0: LN2 stats
    float v0 = s.tvb[tid], v1 = s.tvb[tid + 64];
    float m = wsum64(v0 + v1) * (1.f / ND);
    float d0 = v0 - m, d1 = v1 - m;
    float var = wsum64(d0 * d0 + d1 * d1) * (1.f / ND);
    if (tid == 0) {
      s.stats[0] = m;
      s.stats[1] = rsqrtf(var + LN_EPS);
    }
  }
  __syncthreads();
  if (tid < ND) {
    float o = (s.tvb[tid] - s.stats[0]) * s.stats[1] * g2[tid] + bb2[tid];
    xout[row * ND + tid] = o;  // FLOAT32 output
  }
}

// ---------------- K4: edge stage 1 via MFMA, factored node projections -----
// Per block (b,i), 12 M-tiles of 32 j-rows:
//   L1: [32x256](a_ij|a_ji|x_j) @ W1abc^T (MFMA, hi/lo split)
//       + (x_i @ W1d^T + b1) [per-thread f32xbf16] -> relu -> H1
//   L2: H1 @ W2^T + a_ij ; residual + LN over 64 cols.
#define EMT 32

struct E1M {
  u16 Ahi[EMT][256];   // 16KB swizzled, row stride 512B
  u16 Alo[EMT][256];   // 16KB
  u16 Hhi[EMT][NE];    // 4KB swizzled, row stride 128B
  u16 Hlo[EMT][NE];    // 4KB ; Hhi+Hlo reused as f32 tvb[32][64] for LN
};

__global__ void __launch_bounds__(512) k_edge1(
    const float* __restrict__ adj, const float* __restrict__ xq,
    const float* __restrict__ w1, const float* __restrict__ b1,
    const float* __restrict__ w2, const float* __restrict__ b2,
    const float* __restrict__ g, const float* __restrict__ bb,
    float* __restrict__ adj1out) {
  __shared__ E1M s;
  int bi = blockIdx.x;
  int b = bi / NN, i = bi % NN;
  int t = threadIdx.x;      // 512
  int w = t >> 6, l = t & 63;
  int m16 = (w & 1) * 16;   // wave's M sub-tile base
  int n16 = (w >> 1) * 16;  // wave's N sub-tile base
  int lr = l & 15, lk = l >> 4;

  // per-wave weight fragments (f32 -> bf16 once per block), cols 0..255
  s16x8 B1[8], B2[2];
  {
    const float* wr = w1 + (size_t)(n16 + lr) * EH1 + lk * 8;
#pragma unroll
    for (int ks = 0; ks < 8; ++ks) B1[ks] = cvt_frag(wr + ks * 32);
    const float* w2r = w2 + (size_t)(n16 + lr) * NE + lk * 8;
#pragma unroll
    for (int ks = 0; ks < 2; ++ks) B2[ks] = cvt_frag(w2r + ks * 32);
  }
  // x_i @ W1d^T (cols 256..383), f32 activation x bf16 weight (exact-act).
  float bias1;
  {
    float ci = 0.f;
    const float* xr = xq + (size_t)bi * ND;
    const float* wr = w1 + (size_t)(n16 + lr) * EH1 + 256;
#pragma unroll 4
    for (int k = 0; k < ND; ++k) ci += xr[k] * bfu(bfr(wr[k]));
    bias1 = b1[n16 + lr] + ci;
  }
  float bias2 = b2[n16 + lr];
  float gl = g[l], bl = bb[l];

  for (int mt = 0; mt < NN / EMT; ++mt) {
    int jbase = mt * EMT;
    __syncthreads();
    // stage tile: 32 rows x 32 x 16B units (a_ij 8 | a_ji 8 | x_j 16), hi/lo
    for (int p = t; p < EMT * 32; p += 512) {
      int row = p >> 5, uu = p & 31;
      const float* src;
      if (uu < 8)
        src = adj + ((size_t)bi * NN + jbase + row) * NE + uu * 8;
      else if (uu < 16)
        src = adj + ((size_t)(b * NN + jbase + row) * NN + i) * NE + (uu - 8) * 8;
      else
        src = xq + (size_t)(b * NN + jbase + row) * ND + (uu - 16) * 8;
      uint4 hi, lo;
      cvt8_hl(src, hi, lo);
      int byt = (row * 512 + uu * 16) ^ ((row & 7) << 4);
      *(uint4*)((char*)s.Ahi + byt) = hi;
      *(uint4*)((char*)s.Alo + byt) = lo;
    }
    __syncthreads();

    // layer1: K=256
    f32x4 acc = {0.f, 0.f, 0.f, 0.f};
    int arow = m16 + lr;
    int aswz = (arow & 7) << 4;
#pragma unroll
    for (int ks = 0; ks < 8; ++ks) {
      int byt = (arow * 512 + ks * 64 + lk * 16) ^ aswz;
      s16x8 ah = *(const s16x8*)((const char*)s.Ahi + byt);
      s16x8 al = *(const s16x8*)((const char*)s.Alo + byt);
      acc = MFMA16(ah, B1[ks], acc);
      acc = MFMA16(al, B1[ks], acc);
    }
#pragma unroll
    for (int r = 0; r < 4; ++r) {
      float hv = fmaxf(acc[r] + bias1, 0.f);
      u16 hh = bfr(hv);
      u16 hl = bfr(hv - bfu(hh));
      int row = m16 + lk * 4 + r;
      int byt = (row * 128 + (n16 + lr) * 2) ^ ((row & 7) << 4);
      *(u16*)((char*)s.Hhi + byt) = hh;
      *(u16*)((char*)s.Hlo + byt) = hl;
    }
    __syncthreads();

    // layer2
    f32x4 acc2 = {0.f, 0.f, 0.f, 0.f};
#pragma unroll
    for (int ks = 0; ks < 2; ++ks) {
      int byt = (arow * 128 + ks * 64 + lk * 16) ^ aswz;
      s16x8 ah = *(const s16x8*)((const char*)s.Hhi + byt);
      s16x8 al = *(const s16x8*)((const char*)s.Hlo + byt);
      acc2 = MFMA16(ah, B2[ks], acc2);
      acc2 = MFMA16(al, B2[ks], acc2);
    }
    __syncthreads();  // H reads done -> reuse as f32 tv buffer
    float* tvb = (float*)s.Hhi;
#pragma unroll
    for (int r = 0; r < 4; ++r) {
      int row = m16 + lk * 4 + r;
      int col = n16 + lr;
      int abyt = (row * 512 + col * 2) ^ ((row & 7) << 4);
      float aorig = bfu(*(const u16*)((const char*)s.Ahi + abyt)) +
                    bfu(*(const u16*)((const char*)s.Alo + abyt));
      tvb[row * NE + col] = aorig + acc2[r] + bias2;
    }
    __syncthreads();
    // LN: wave w handles rows w*4..w*4+3, lane = col
#pragma unroll
    for (int rr = 0; rr < EMT / 8; ++rr) {
      int row = w * (EMT / 8) + rr;
      float tv = tvb[row * NE + l];
      float mean = wsum64(tv) * (1.f / NE);
      float dv = tv - mean;
      float var = wsum64(dv * dv) * (1.f / NE);
      float o = dv * rsqrtf(var + LN_EPS) * gl + bl;
      adj1out[((size_t)bi * NN + jbase + row) * NE + l] = o;
    }
  }
}

// ---------------- K5: edge stage 2 via MFMA (in-place on d_out adj) --------
struct E2M {
  u16 Ahi[EMT][NE];    // 4KB swizzled, row stride 128B
  u16 Alo[EMT][NE];    // 4KB
  u16 Hhi[EMT][EH2];   // 8KB swizzled, row stride 256B ; reused as f32 tvb
  u16 Hlo[EMT][EH2];   // 8KB
};

__global__ void __launch_bounds__(512) k_edge2(
    float* __restrict__ adjio,
    const float* __restrict__ w3, const float* __restrict__ b3,
    const float* __restrict__ w4, const float* __restrict__ b4,
    const float* __restrict__ g, const float* __restrict__ bb) {
  __shared__ E2M s;
  int bi = blockIdx.x;
  int t = threadIdx.x;      // 512
  int w = t >> 6, l = t & 63;
  int m16 = (w & 1) * 16;
  int nb = (w >> 1) * 2;    // layer3 n16 pair base (0,2,4,6)
  int n16 = (w >> 1) * 16;  // layer4 col base
  int lr = l & 15, lk = l >> 4;

  s16x8 B3[2][2], B4[4];
  {
#pragma unroll
    for (int n = 0; n < 2; ++n) {
      const float* wr = w3 + (size_t)((nb + n) * 16 + lr) * NE + lk * 8;
#pragma unroll
      for (int ks = 0; ks < 2; ++ks) B3[n][ks] = cvt_frag(wr + ks * 32);
    }
    const float* w4r = w4 + (size_t)(n16 + lr) * EH2 + lk * 8;
#pragma unroll
    for (int ks = 0; ks < 4; ++ks) B4[ks] = cvt_frag(w4r + ks * 32);
  }
  float bias3[2] = {b3[nb * 16 + lr], b3[(nb + 1) * 16 + lr]};
  float bias4 = b4[n16 + lr];
  float gl = g[l], bl = bb[l];

  for (int mt = 0; mt < NN / EMT; ++mt) {
    int jbase = mt * EMT;
    __syncthreads();
    for (int p = t; p < EMT * 8; p += 512) {  // 256 units, threads<256 active
      int row = p >> 3, u = p & 7;
      const float* src = adjio + ((size_t)bi * NN + jbase + row) * NE + u * 8;
      uint4 hi, lo;
      cvt8_hl(src, hi, lo);
      int byt = (row * 128 + u * 16) ^ ((row & 7) << 4);
      *(uint4*)((char*)s.Ahi + byt) = hi;
      *(uint4*)((char*)s.Alo + byt) = lo;
    }
    __syncthreads();

    // layer3: out [32 x 128]
    f32x4 a3[2] = {{0.f, 0.f, 0.f, 0.f}, {0.f, 0.f, 0.f, 0.f}};
    int arow = m16 + lr;
    int aswz = (arow & 7) << 4;
#pragma unroll
    for (int ks = 0; ks < 2; ++ks) {
      int byt = (arow * 128 + ks * 64 + lk * 16) ^ aswz;
      s16x8 ah = *(const s16x8*)((const char*)s.Ahi + byt);
      s16x8 al = *(const s16x8*)((const char*)s.Alo + byt);
#pragma unroll
      for (int n = 0; n < 2; ++n) {
        a3[n] = MFMA16(ah, B3[n][ks], a3[n]);
        a3[n] = MFMA16(al, B3[n][ks], a3[n]);
      }
    }
#pragma unroll
    for (int n = 0; n < 2; ++n) {
#pragma unroll
      for (int r = 0; r < 4; ++r) {
        float hv = fmaxf(a3[n][r] + bias3[n], 0.f);
        u16 hh = bfr(hv);
        u16 hl = bfr(hv - bfu(hh));
        int row = m16 + lk * 4 + r;
        int byt = (row * 256 + ((nb + n) * 16 + lr) * 2) ^ ((row & 7) << 4);
        *(u16*)((char*)s.Hhi + byt) = hh;
        *(u16*)((char*)s.Hlo + byt) = hl;
      }
    }
    __syncthreads();

    // layer4: out [32 x 64]
    f32x4 a4 = {0.f, 0.f, 0.f, 0.f};
#pragma unroll
    for (int ks = 0; ks < 4; ++ks) {
      int byt = (arow * 256 + ks * 64 + lk * 16) ^ aswz;
      s16x8 ah = *(const s16x8*)((const char*)s.Hhi + byt);
      s16x8 al = *(const s16x8*)((const char*)s.Hlo + byt);
      a4 = MFMA16(ah, B4[ks], a4);
      a4 = MFMA16(al, B4[ks], a4);
    }
    __syncthreads();  // H reads done -> reuse as f32 tv buffer
    float* tvb = (float*)s.Hhi;
#pragma unroll
    for (int r = 0; r < 4; ++r) {
      int row = m16 + lk * 4 + r;
      int col = n16 + lr;
      int abyt = (row * 128 + col * 2) ^ ((row & 7) << 4);
      float aorig = bfu(*(const u16*)((const char*)s.Ahi + abyt)) +
                    bfu(*(const u16*)((const char*)s.Alo + abyt));
      tvb[row * NE + col] = aorig + a4[r] + bias4;
    }
    __syncthreads();
#pragma unroll
    for (int rr = 0; rr < EMT / 8; ++rr) {
      int row = w * (EMT / 8) + rr;
      float tv = tvb[row * NE + l];
      float mean = wsum64(tv) * (1.f / NE);
      float dv = tv - mean;
      float var = wsum64(dv * dv) * (1.f / NE);
      float o = dv * rsqrtf(var + LN_EPS) * gl + bl;
      adjio[((size_t)bi * NN + jbase + row) * NE + l] = o;
    }
  }
}

extern "C" void kernel_launch(void* const* d_in, const int* in_sizes, int n_in,
                              void* d_out, int out_size, void* d_ws, size_t ws_size,
                              hipStream_t stream) {
  (void)in_sizes; (void)n_in; (void)out_size; (void)d_ws; (void)ws_size;
  const float* x      = (const float*)d_in[0];
  const float* adj    = (const float*)d_in[1];
  const float* wnq    = (const float*)d_in[2];
  const float* wnk    = (const float*)d_in[3];
  const float* wnv    = (const float*)d_in[4];
  const float* weq    = (const float*)d_in[5];
  const float* wek    = (const float*)d_in[6];
  const float* wev    = (const float*)d_in[7];
  const float* nfc1_w = (const float*)d_in[8];
  const float* nfc1_b = (const float*)d_in[9];
  const float* ln1_g  = (const float*)d_in[10];
  const float* ln1_b  = (const float*)d_in[11];
  const float* nfc2_w = (const float*)d_in[12];
  const float* nfc2_b = (const float*)d_in[13];
  const float* nfc3_w = (const float*)d_in[14];
  const float* nfc3_b = (const float*)d_in[15];
  const float* ln2_g  = (const float*)d_in[16];
  const float* ln2_b  = (const float*)d_in[17];
  const float* efc1_w = (const float*)d_in[18];
  const float* efc1_b = (const float*)d_in[19];
  const float* efc2_w = (const float*)d_in[20];
  const float* efc2_b = (const float*)d_in[21];
  const float* eln1_g = (const float*)d_in[22];
  const float* eln1_b = (const float*)d_in[23];
  const float* efc3_w = (const float*)d_in[24];
  const float* efc3_b = (const float*)d_in[25];
  const float* efc4_w = (const float*)d_in[26];
  const float* efc4_b = (const float*)d_in[27];
  const float* eln2_g = (const float*)d_in[28];
  const float* eln2_b = (const float*)d_in[29];

  float* outf = (float*)d_out;          // FLOAT32 output buffer: [x ; adj]
  float* outadj = outf + XOUT_ELEMS;

  // f32 scratch in the tail of the adj-output region (dead until k_edge1).
  float* scratch = outf + OUT_ELEMS - SCRATCH_F32;
  float* nq  = scratch;
  float* nk  = scratch + XOUT_ELEMS;
  float* nv  = scratch + 2 * XOUT_ELEMS;
  float* att = scratch + 3 * XOUT_ELEMS;

  k_node_qkv<<<NB * NN, 128, 0, stream>>>(x, wnq, wnk, wnv, nq, nk, nv);
  k_attn<<<NB * NN, 512, 0, stream>>>(adj, weq, wek, wev, nq, nk, nv, att);
  k_node_ffn<<<NB * NN, 256, 0, stream>>>(x, att, nfc1_w, nfc1_b, ln1_g, ln1_b,
                                          nfc2_w, nfc2_b, nfc3_w, nfc3_b,
                                          ln2_g, ln2_b, outf);
  k_edge1<<<NB * NN, 512, 0, stream>>>(adj, outf, efc1_w, efc1_b, efc2_w, efc2_b,
                                       eln1_g, eln1_b, outadj);
  k_edge2<<<NB * NN, 512, 0, stream>>>(outadj, efc3_w, efc3_b, efc4_w, efc4_b,
                                       eln2_g, eln2_b);
}